// Round 8
// baseline (297.112 us; speedup 1.0000x reference)
//
#include <hip/hip_runtime.h>

typedef unsigned short u16;
typedef __attribute__((ext_vector_type(8))) _Float16 f16x8;
typedef __attribute__((ext_vector_type(4))) float f32x4;

#define MFMA_F16 __builtin_amdgcn_mfma_f32_16x16x32_f16

static __device__ __forceinline__ u16 f2h(float f) {
    return __builtin_bit_cast(u16, (_Float16)f);
}
static __device__ __forceinline__ ushort4 f4_to_h4(const float4 v) {
    ushort4 r;
    r.x = f2h(v.x); r.y = f2h(v.y); r.z = f2h(v.z); r.w = f2h(v.w);
    return r;
}

// ---------------------------------------------------------------------------
// Kernel 0: prep — convert x (4.19M) and Wq/Wk/Wv/Wo (4x65536) fp32 -> fp16.
// (identical to round-6 passing version)
// ---------------------------------------------------------------------------
__global__ __launch_bounds__(256) void prep(
    const float* __restrict__ x,
    const float* __restrict__ wq, const float* __restrict__ wk,
    const float* __restrict__ wv, const float* __restrict__ wo,
    u16* __restrict__ xh, u16* __restrict__ w4)
{
    const int tid = blockIdx.x * 256 + threadIdx.x;
    for (int i = tid; i < 1048576; i += 2048 * 256)
        ((ushort4*)xh)[i] = f4_to_h4(((const float4*)x)[i]);
    if (blockIdx.x < 64) {
        for (int i = tid; i < 65536; i += 16384) {
            const float* src = (i < 16384) ? wq : (i < 32768) ? wk
                             : (i < 49152) ? wv : wo;
            ((ushort4*)w4)[i] = f4_to_h4(((const float4*)src)[i & 16383]);
        }
    }
}

// ---------------------------------------------------------------------------
// Kernel 1: Q/K/V projection, fp16.  (identical to round-6 passing version)
// ---------------------------------------------------------------------------
__global__ __launch_bounds__(256) void proj_qkv(
    const u16* __restrict__ xh, const u16* __restrict__ w4,
    const float* __restrict__ bq, const float* __restrict__ bk,
    const float* __restrict__ bv,
    u16* __restrict__ Qh, u16* __restrict__ Kh, u16* __restrict__ V)
{
    const int z = blockIdx.y;
    const u16* __restrict__ W     = w4 + z * 65536;
    const float* __restrict__ bias = (z == 0) ? bq : (z == 1) ? bk : bv;
    u16* __restrict__ Y            = (z == 0) ? Qh : (z == 1) ? Kh : V;

    const int m0   = blockIdx.x * 64;
    const int t    = threadIdx.x;
    const int w    = t >> 6;
    const int lane = t & 63;
    const int quad = lane >> 4;
    const int l16  = lane & 15;

    __shared__ __align__(16) u16 Xs[64 * 40];
    __shared__ __align__(16) u16 Ws[256 * 40];

    f32x4 acc[16];
#pragma unroll
    for (int i = 0; i < 16; ++i) acc[i] = f32x4{0.f, 0.f, 0.f, 0.f};

    for (int kc = 0; kc < 8; ++kc) {
        {
            const int row = t >> 2, cg = t & 3;
            *(int4*)&Xs[row * 40 + cg * 8] =
                *(const int4*)&xh[(size_t)(m0 + row) * 256 + kc * 32 + cg * 8];
        }
#pragma unroll
        for (int i = 0; i < 4; ++i) {
            const int ch = i * 256 + t;
            const int row = ch >> 2, cg = ch & 3;
            *(int4*)&Ws[row * 40 + cg * 8] =
                *(const int4*)&W[(size_t)row * 256 + kc * 32 + cg * 8];
        }
        __syncthreads();

        const f16x8 af = *(const f16x8*)&Xs[(w * 16 + l16) * 40 + quad * 8];
#pragma unroll
        for (int nt = 0; nt < 16; ++nt) {
            const f16x8 bf = *(const f16x8*)&Ws[(nt * 16 + l16) * 40 + quad * 8];
            acc[nt] = MFMA_F16(af, bf, acc[nt], 0, 0, 0);
        }
        __syncthreads();
    }

#pragma unroll
    for (int nt = 0; nt < 16; ++nt) {
        const int col = nt * 16 + l16;
        const float bb = bias[col];
#pragma unroll
        for (int r = 0; r < 4; ++r) {
            const int row = m0 + w * 16 + quad * 4 + r;
            Y[(size_t)row * 256 + col] = f2h(acc[nt][r] + bb);
        }
    }
}

// ---------------------------------------------------------------------------
// Kernel 2: per-batch transpose V[b][n][d] -> Vt[b][d][n]   (fp16)
// ---------------------------------------------------------------------------
__global__ __launch_bounds__(256) void transpose_v(
    const u16* __restrict__ V, u16* __restrict__ Vt)
{
    __shared__ u16 tile[32][33];
    const int b  = blockIdx.z;
    const int n0 = blockIdx.x * 32;
    const int d0 = blockIdx.y * 32;
    const int tx = threadIdx.x;
    const int ty = threadIdx.y;
#pragma unroll
    for (int i = 0; i < 4; ++i)
        tile[ty + 8 * i][tx] =
            V[(size_t)(b * 2048 + n0 + ty + 8 * i) * 256 + d0 + tx];
    __syncthreads();
#pragma unroll
    for (int i = 0; i < 4; ++i)
        Vt[(size_t)b * 524288 + (size_t)(d0 + ty + 8 * i) * 2048 + n0 + tx] =
            tile[tx][ty + 8 * i];
}

// ---------------------------------------------------------------------------
// Kernel 3: flash attention, fp16, split-K x2.
// = round-6 passing kernel + register prefetch of the next K/V tile
// (ONLY change vs round 6; softmax/l-sum/barriers identical to round 6).
// ---------------------------------------------------------------------------
__global__ __launch_bounds__(256) void attn(
    const u16* __restrict__ Qh, const u16* __restrict__ Kg,
    const u16* __restrict__ Vt, u16* __restrict__ Op, float* __restrict__ lmp)
{
    const int b  = blockIdx.y;
    const int q0 = blockIdx.x * 64;
    const int z  = blockIdx.z;
    const int kbase = z * 1024;
    const int t    = threadIdx.x;
    const int w    = t >> 6;
    const int lane = t & 63;
    const int quad = lane >> 4;
    const int l16  = lane & 15;

    __shared__ __align__(16) u16 Ks[32 * 264];     // 32 keys x 256 (+8 pad)
    __shared__ __align__(16) u16 Vs[256 * 40];     // 256 dv x 32 keys (+8)
    __shared__ __align__(16) u16 Ps[4][16 * 40];   // per-wave P

    f16x8 qf[8];
    {
        const size_t qrow = (size_t)(b * 2048 + q0 + w * 16 + l16) * 256;
#pragma unroll
        for (int kc = 0; kc < 8; ++kc)
            qf[kc] = *(const f16x8*)&Qh[qrow + kc * 32 + quad * 8];
    }

    f32x4 O[16];
#pragma unroll
    for (int i = 0; i < 16; ++i) O[i] = f32x4{0.f, 0.f, 0.f, 0.f};
    float mrow[4], lrow[4];
#pragma unroll
    for (int r = 0; r < 4; ++r) { mrow[r] = -1e30f; lrow[r] = 0.f; }

    // per-thread staging coordinates (same coverage as round 6)
    const int krow = t >> 5, kcg = t & 31;   // K: rows i*8+krow, cols kcg*8
    const int vrow = t >> 2, vcg = t & 3;    // V: rows i*64+vrow, cols vcg*8

    int4 kreg[4], vreg[4];
#pragma unroll
    for (int i = 0; i < 4; ++i) {
        kreg[i] = *(const int4*)&Kg[(size_t)(b * 2048 + kbase + i * 8 + krow) * 256 + kcg * 8];
        vreg[i] = *(const int4*)&Vt[(size_t)b * 524288 + (size_t)(i * 64 + vrow) * 2048 + kbase + vcg * 8];
    }

    for (int it = 0; it < 32; ++it) {
        // write staged registers into LDS (regs hold tile `it`)
#pragma unroll
        for (int i = 0; i < 4; ++i) {
            *(int4*)&Ks[(i * 8 + krow) * 264 + kcg * 8] = kreg[i];
            *(int4*)&Vs[(i * 64 + vrow) * 40 + vcg * 8] = vreg[i];
        }
        __syncthreads();

        // prefetch tile it+1 while computing tile it
        if (it + 1 < 32) {
            const int kt0 = (it + 1) * 32;
#pragma unroll
            for (int i = 0; i < 4; ++i) {
                kreg[i] = *(const int4*)&Kg[(size_t)(b * 2048 + kbase + kt0 + i * 8 + krow) * 256 + kcg * 8];
                vreg[i] = *(const int4*)&Vt[(size_t)b * 524288 + (size_t)(i * 64 + vrow) * 2048 + kbase + kt0 + vcg * 8];
            }
        }

        f32x4 S[2];
        S[0] = f32x4{0.f, 0.f, 0.f, 0.f};
        S[1] = f32x4{0.f, 0.f, 0.f, 0.f};
#pragma unroll
        for (int kc = 0; kc < 8; ++kc) {
#pragma unroll
            for (int kn = 0; kn < 2; ++kn) {
                const f16x8 bf = *(const f16x8*)&Ks[(kn * 16 + l16) * 264 + kc * 32 + quad * 8];
                S[kn] = MFMA_F16(qf[kc], bf, S[kn], 0, 0, 0);
            }
        }

        // online softmax — round-6 immediate form (shuffle l-sum per tile)
        float P[2][4], a4[4];
#pragma unroll
        for (int r = 0; r < 4; ++r) {
            float mt = fmaxf(S[0][r], S[1][r]);
            mt = fmaxf(mt, __shfl_xor(mt, 1));
            mt = fmaxf(mt, __shfl_xor(mt, 2));
            mt = fmaxf(mt, __shfl_xor(mt, 4));
            mt = fmaxf(mt, __shfl_xor(mt, 8));
            const float mnew = fmaxf(mrow[r], mt);
            a4[r] = __expf(mrow[r] - mnew);
            const float p0 = __expf(S[0][r] - mnew);
            const float p1 = __expf(S[1][r] - mnew);
            float s = p0 + p1;
            s += __shfl_xor(s, 1);
            s += __shfl_xor(s, 2);
            s += __shfl_xor(s, 4);
            s += __shfl_xor(s, 8);
            lrow[r] = a4[r] * lrow[r] + s;
            mrow[r] = mnew;
            P[0][r] = p0; P[1][r] = p1;
        }
        if (a4[0] < 1.f || a4[1] < 1.f || a4[2] < 1.f || a4[3] < 1.f) {
#pragma unroll
            for (int dv = 0; dv < 16; ++dv)
#pragma unroll
                for (int r = 0; r < 4; ++r) O[dv][r] *= a4[r];
        }

        // P: C/D layout -> per-wave LDS -> A layout (wave-local fence)
#pragma unroll
        for (int kn = 0; kn < 2; ++kn)
#pragma unroll
            for (int r = 0; r < 4; ++r)
                Ps[w][(quad * 4 + r) * 40 + kn * 16 + l16] = f2h(P[kn][r]);
        asm volatile("s_waitcnt lgkmcnt(0)" ::: "memory");

        const f16x8 af = *(const f16x8*)&Ps[w][l16 * 40 + quad * 8];
#pragma unroll
        for (int dv = 0; dv < 16; ++dv) {
            const f16x8 bf = *(const f16x8*)&Vs[(dv * 16 + l16) * 40 + quad * 8];
            O[dv] = MFMA_F16(af, bf, O[dv], 0, 0, 0);
        }
        __syncthreads();
    }

    u16* __restrict__ Oz = Op + (size_t)z * 4194304;
#pragma unroll
    for (int r = 0; r < 4; ++r) {
        const float rl = 1.0f / lrow[r];
        const int grow = b * 2048 + q0 + w * 16 + quad * 4 + r;
        const size_t rowoff = (size_t)grow * 256;
#pragma unroll
        for (int dv = 0; dv < 16; ++dv)
            Oz[rowoff + dv * 16 + l16] = f2h(O[dv][r] * rl);
        if (l16 == 0) {
            lmp[z * 16384 + grow]         = lrow[r];
            lmp[32768 + z * 16384 + grow] = mrow[r];
        }
    }
}

// ---------------------------------------------------------------------------
// Kernel 4: combine + out projection + LayerNorm + LeakyReLU.
// (identical to round-6 passing version: BM=64, 256 threads)
// ---------------------------------------------------------------------------
__global__ __launch_bounds__(256) void outproj_ln(
    const u16* __restrict__ Op, const float* __restrict__ lmp,
    const u16* __restrict__ Woh, const float* __restrict__ bo,
    const float* __restrict__ gamma, const float* __restrict__ beta,
    float* __restrict__ out)
{
    const int m0   = blockIdx.x * 64;
    const int t    = threadIdx.x;
    const int w    = t >> 6;
    const int lane = t & 63;
    const int quad = lane >> 4;
    const int l16  = lane & 15;

    __shared__ __align__(16) u16 Ls[64 * 40];
    __shared__ __align__(16) u16 Ws[256 * 40];
    __shared__ _Float16 w0s[64], w1s[64];

    if (t < 64) {
        const float l0 = lmp[m0 + t],          l1 = lmp[16384 + m0 + t];
        const float mm0 = lmp[32768 + m0 + t], mm1 = lmp[49152 + m0 + t];
        const float mm = fmaxf(mm0, mm1);
        const float u0 = l0 * __expf(mm0 - mm);
        const float u1 = l1 * __expf(mm1 - mm);
        const float inv = 1.0f / (u0 + u1);
        w0s[t] = (_Float16)(u0 * inv);
        w1s[t] = (_Float16)(u1 * inv);
    }
    __syncthreads();

    f32x4 acc[16];
#pragma unroll
    for (int i = 0; i < 16; ++i) acc[i] = f32x4{0.f, 0.f, 0.f, 0.f};

    for (int kc = 0; kc < 8; ++kc) {
        {
            const int row = t >> 2, cg = t & 3;
            const size_t off = (size_t)(m0 + row) * 256 + kc * 32 + cg * 8;
            const f16x8 o0 = __builtin_bit_cast(f16x8, *(const int4*)&Op[off]);
            const f16x8 o1 = __builtin_bit_cast(f16x8, *(const int4*)&Op[4194304 + off]);
            const _Float16 w0 = w0s[row], w1 = w1s[row];
            f16x8 lw;
#pragma unroll
            for (int j = 0; j < 8; ++j) lw[j] = o0[j] * w0 + o1[j] * w1;
            *(int4*)&Ls[row * 40 + cg * 8] = __builtin_bit_cast(int4, lw);
        }
#pragma unroll
        for (int i = 0; i < 4; ++i) {
            const int ch = i * 256 + t;
            const int row = ch >> 2, cg = ch & 3;
            *(int4*)&Ws[row * 40 + cg * 8] =
                *(const int4*)&Woh[(size_t)row * 256 + kc * 32 + cg * 8];
        }
        __syncthreads();

        const f16x8 af = *(const f16x8*)&Ls[(w * 16 + l16) * 40 + quad * 8];
#pragma unroll
        for (int nt = 0; nt < 16; ++nt) {
            const f16x8 bf = *(const f16x8*)&Ws[(nt * 16 + l16) * 40 + quad * 8];
            acc[nt] = MFMA_F16(af, bf, acc[nt], 0, 0, 0);
        }
        __syncthreads();
    }

    float g[16], bt[16], bb[16];
#pragma unroll
    for (int nt = 0; nt < 16; ++nt) {
        const int col = nt * 16 + l16;
        bb[nt] = bo[col]; g[nt] = gamma[col]; bt[nt] = beta[col];
    }

#pragma unroll
    for (int r = 0; r < 4; ++r) {
        float h[16];
        float sh = 0.f, sh2 = 0.f;
#pragma unroll
        for (int nt = 0; nt < 16; ++nt) {
            h[nt] = acc[nt][r] + bb[nt];
            sh  += h[nt];
            sh2 += h[nt] * h[nt];
        }
        sh  += __shfl_xor(sh, 1);  sh  += __shfl_xor(sh, 2);
        sh  += __shfl_xor(sh, 4);  sh  += __shfl_xor(sh, 8);
        sh2 += __shfl_xor(sh2, 1); sh2 += __shfl_xor(sh2, 2);
        sh2 += __shfl_xor(sh2, 4); sh2 += __shfl_xor(sh2, 8);
        const float mu  = sh * (1.f / 256.f);
        const float var = fmaxf(sh2 * (1.f / 256.f) - mu * mu, 0.f);
        const float rs  = rsqrtf(var + 1e-5f);
        const size_t row = (size_t)(m0 + w * 16 + quad * 4 + r) * 256;
#pragma unroll
        for (int nt = 0; nt < 16; ++nt) {
            const float hn = (h[nt] - mu) * rs * g[nt] + bt[nt];
            out[row + nt * 16 + l16] = (hn >= 0.f) ? hn : 0.01f * hn;
        }
    }
}

// ---------------------------------------------------------------------------
extern "C" void kernel_launch(void* const* d_in, const int* in_sizes, int n_in,
                              void* d_out, int out_size, void* d_ws, size_t ws_size,
                              hipStream_t stream)
{
    const float* x  = (const float*)d_in[0];
    const float* Wq = (const float*)d_in[1];
    const float* bq = (const float*)d_in[2];
    const float* Wk = (const float*)d_in[3];
    const float* bk = (const float*)d_in[4];
    const float* Wv = (const float*)d_in[5];
    const float* bv = (const float*)d_in[6];
    const float* Wo = (const float*)d_in[7];
    const float* bo = (const float*)d_in[8];
    const float* gm = (const float*)d_in[9];
    const float* bt = (const float*)d_in[10];
    float* out = (float*)d_out;

    // ws layout (u16 units). Op overlays dead V+xh regions:
    //   [W4 262144][Qh 4.19M][Kh 4.19M][Vt 4.19M][V 4.19M][xh 4.19M][lmp]
    u16* W4 = (u16*)d_ws;
    u16* Qh = W4 + 262144;
    u16* Kh = Qh + 4194304;
    u16* Vt = Kh + 4194304;
    u16* V  = Vt + 4194304;
    u16* xh = V  + 4194304;
    u16* Op = V;                          // 2 x 4194304 (overlays V, xh)
    float* lmp = (float*)(xh + 4194304);  // l[2][16384], m[2][16384]
    u16* Woh = W4 + 196608;

    prep       <<<2048,           256,        0, stream>>>(x, Wq, Wk, Wv, Wo, xh, W4);
    proj_qkv   <<<dim3(256, 3),   256,        0, stream>>>(xh, W4, bq, bk, bv, Qh, Kh, V);
    transpose_v<<<dim3(64, 8, 8), dim3(32,8), 0, stream>>>(V, Vt);
    attn       <<<dim3(32, 8, 2), 256,        0, stream>>>(Qh, Kh, Vt, Op, lmp);
    outproj_ln <<<256,            256,        0, stream>>>(Op, lmp, Woh, bo, gm, bt, out);
}

// Round 9
// 283.959 us; speedup vs baseline: 1.0463x; 1.0463x over previous
//
#include <hip/hip_runtime.h>

typedef unsigned short u16;
typedef __attribute__((ext_vector_type(8))) _Float16 f16x8;
typedef __attribute__((ext_vector_type(4))) float f32x4;

#define MFMA_F16 __builtin_amdgcn_mfma_f32_16x16x32_f16

static __device__ __forceinline__ u16 f2h(float f) {
    return __builtin_bit_cast(u16, (_Float16)f);
}
static __device__ __forceinline__ ushort4 f4_to_h4(const float4 v) {
    ushort4 r;
    r.x = f2h(v.x); r.y = f2h(v.y); r.z = f2h(v.z); r.w = f2h(v.w);
    return r;
}

// ---------------------------------------------------------------------------
// Kernel 0: prep — convert x and Wq/Wk/Wv/Wo fp32 -> fp16. (R6/R8 passing)
// ---------------------------------------------------------------------------
__global__ __launch_bounds__(256) void prep(
    const float* __restrict__ x,
    const float* __restrict__ wq, const float* __restrict__ wk,
    const float* __restrict__ wv, const float* __restrict__ wo,
    u16* __restrict__ xh, u16* __restrict__ w4)
{
    const int tid = blockIdx.x * 256 + threadIdx.x;
    for (int i = tid; i < 1048576; i += 2048 * 256)
        ((ushort4*)xh)[i] = f4_to_h4(((const float4*)x)[i]);
    if (blockIdx.x < 64) {
        for (int i = tid; i < 65536; i += 16384) {
            const float* src = (i < 16384) ? wq : (i < 32768) ? wk
                             : (i < 49152) ? wv : wo;
            ((ushort4*)w4)[i] = f4_to_h4(((const float4*)src)[i & 16383]);
        }
    }
}

// ---------------------------------------------------------------------------
// Kernel 1: Q/K/V projection, fp16. (R6/R8 passing version, unchanged)
// ---------------------------------------------------------------------------
__global__ __launch_bounds__(256) void proj_qkv(
    const u16* __restrict__ xh, const u16* __restrict__ w4,
    const float* __restrict__ bq, const float* __restrict__ bk,
    const float* __restrict__ bv,
    u16* __restrict__ Qh, u16* __restrict__ Kh, u16* __restrict__ V)
{
    const int z = blockIdx.y;
    const u16* __restrict__ W     = w4 + z * 65536;
    const float* __restrict__ bias = (z == 0) ? bq : (z == 1) ? bk : bv;
    u16* __restrict__ Y            = (z == 0) ? Qh : (z == 1) ? Kh : V;

    const int m0   = blockIdx.x * 64;
    const int t    = threadIdx.x;
    const int w    = t >> 6;
    const int lane = t & 63;
    const int quad = lane >> 4;
    const int l16  = lane & 15;

    __shared__ __align__(16) u16 Xs[64 * 40];
    __shared__ __align__(16) u16 Ws[256 * 40];

    f32x4 acc[16];
#pragma unroll
    for (int i = 0; i < 16; ++i) acc[i] = f32x4{0.f, 0.f, 0.f, 0.f};

    for (int kc = 0; kc < 8; ++kc) {
        {
            const int row = t >> 2, cg = t & 3;
            *(int4*)&Xs[row * 40 + cg * 8] =
                *(const int4*)&xh[(size_t)(m0 + row) * 256 + kc * 32 + cg * 8];
        }
#pragma unroll
        for (int i = 0; i < 4; ++i) {
            const int ch = i * 256 + t;
            const int row = ch >> 2, cg = ch & 3;
            *(int4*)&Ws[row * 40 + cg * 8] =
                *(const int4*)&W[(size_t)row * 256 + kc * 32 + cg * 8];
        }
        __syncthreads();

        const f16x8 af = *(const f16x8*)&Xs[(w * 16 + l16) * 40 + quad * 8];
#pragma unroll
        for (int nt = 0; nt < 16; ++nt) {
            const f16x8 bf = *(const f16x8*)&Ws[(nt * 16 + l16) * 40 + quad * 8];
            acc[nt] = MFMA_F16(af, bf, acc[nt], 0, 0, 0);
        }
        __syncthreads();
    }

#pragma unroll
    for (int nt = 0; nt < 16; ++nt) {
        const int col = nt * 16 + l16;
        const float bb = bias[col];
#pragma unroll
        for (int r = 0; r < 4; ++r) {
            const int row = m0 + w * 16 + quad * 4 + r;
            Y[(size_t)row * 256 + col] = f2h(acc[nt][r] + bb);
        }
    }
}

// ---------------------------------------------------------------------------
// Kernel 2: per-batch transpose V[b][n][d] -> Vt[b][d][n]   (fp16)
// ---------------------------------------------------------------------------
__global__ __launch_bounds__(256) void transpose_v(
    const u16* __restrict__ V, u16* __restrict__ Vt)
{
    __shared__ u16 tile[32][33];
    const int b  = blockIdx.z;
    const int n0 = blockIdx.x * 32;
    const int d0 = blockIdx.y * 32;
    const int tx = threadIdx.x;
    const int ty = threadIdx.y;
#pragma unroll
    for (int i = 0; i < 4; ++i)
        tile[ty + 8 * i][tx] =
            V[(size_t)(b * 2048 + n0 + ty + 8 * i) * 256 + d0 + tx];
    __syncthreads();
#pragma unroll
    for (int i = 0; i < 4; ++i)
        Vt[(size_t)b * 524288 + (size_t)(d0 + ty + 8 * i) * 2048 + n0 + tx] =
            tile[tx][ty + 8 * i];
}

// ---------------------------------------------------------------------------
// Kernel 3: flash attention, fp16, split-K x2, q-tile 32, dv-split waves.
// 4 waves: w -> (qhalf = w>>1, dvh = w&1). Pair waves compute identical
// 16x32 scores+softmax (bit-identical -> shared Ps duplicate-write is
// benign); each handles half the dv columns (O[8] = 32 acc regs, no spill).
// LDS 39936 B -> 4 blocks/CU; grid 1024 -> 4 blocks/CU resident.
// NO register prefetch (R8's spill source).
// ---------------------------------------------------------------------------
__global__ __launch_bounds__(256) void attn(
    const u16* __restrict__ Qh, const u16* __restrict__ Kg,
    const u16* __restrict__ Vt, u16* __restrict__ Op, float* __restrict__ lmp)
{
    const int b  = blockIdx.y;
    const int q0 = blockIdx.x * 32;
    const int z  = blockIdx.z;
    const int kbase = z * 1024;
    const int t     = threadIdx.x;
    const int w     = t >> 6;
    const int qhalf = w >> 1;
    const int dvh   = w & 1;
    const int lane  = t & 63;
    const int quad  = lane >> 4;
    const int l16   = lane & 15;

    __shared__ __align__(16) u16 Ks[32 * 264];   // 32 keys x 256 (+8 pad)
    __shared__ __align__(16) u16 Vs[256 * 40];   // 256 dv x 32 keys (+8)
    __shared__ __align__(16) u16 Ps[2][16 * 40]; // per-qhalf P (shared by pair)

    f16x8 qf[8];
    {
        const size_t qrow = (size_t)(b * 2048 + q0 + qhalf * 16 + l16) * 256;
#pragma unroll
        for (int kc = 0; kc < 8; ++kc)
            qf[kc] = *(const f16x8*)&Qh[qrow + kc * 32 + quad * 8];
    }

    f32x4 O[8];
#pragma unroll
    for (int i = 0; i < 8; ++i) O[i] = f32x4{0.f, 0.f, 0.f, 0.f};
    float mrow[4], lrow[4];
#pragma unroll
    for (int r = 0; r < 4; ++r) { mrow[r] = -1e30f; lrow[r] = 0.f; }

    for (int it = 0; it < 32; ++it) {
        const int kt0 = it * 32;
        // stage K tile: 1024 int4-chunks, 4/thread
#pragma unroll
        for (int i = 0; i < 4; ++i) {
            const int ch = i * 256 + t;
            const int row = ch >> 5, cg = ch & 31;
            *(int4*)&Ks[row * 264 + cg * 8] =
                *(const int4*)&Kg[(size_t)(b * 2048 + kbase + kt0 + row) * 256 + cg * 8];
        }
        // stage Vt tile: 1024 int4-chunks, 4/thread
#pragma unroll
        for (int i = 0; i < 4; ++i) {
            const int ch = i * 256 + t;
            const int row = ch >> 2, cg = ch & 3;
            *(int4*)&Vs[row * 40 + cg * 8] =
                *(const int4*)&Vt[(size_t)b * 524288 + (size_t)row * 2048 + kbase + kt0 + cg * 8];
        }
        __syncthreads();

        f32x4 S[2];
        S[0] = f32x4{0.f, 0.f, 0.f, 0.f};
        S[1] = f32x4{0.f, 0.f, 0.f, 0.f};
#pragma unroll
        for (int kc = 0; kc < 8; ++kc) {
#pragma unroll
            for (int kn = 0; kn < 2; ++kn) {
                const f16x8 bf = *(const f16x8*)&Ks[(kn * 16 + l16) * 264 + kc * 32 + quad * 8];
                S[kn] = MFMA_F16(qf[kc], bf, S[kn], 0, 0, 0);
            }
        }

        // online softmax (R6 immediate form; rows quad*4+r across 16 lanes)
        float P[2][4], a4[4];
#pragma unroll
        for (int r = 0; r < 4; ++r) {
            float mt = fmaxf(S[0][r], S[1][r]);
            mt = fmaxf(mt, __shfl_xor(mt, 1));
            mt = fmaxf(mt, __shfl_xor(mt, 2));
            mt = fmaxf(mt, __shfl_xor(mt, 4));
            mt = fmaxf(mt, __shfl_xor(mt, 8));
            const float mnew = fmaxf(mrow[r], mt);
            a4[r] = __expf(mrow[r] - mnew);
            const float p0 = __expf(S[0][r] - mnew);
            const float p1 = __expf(S[1][r] - mnew);
            float s = p0 + p1;
            s += __shfl_xor(s, 1);
            s += __shfl_xor(s, 2);
            s += __shfl_xor(s, 4);
            s += __shfl_xor(s, 8);
            lrow[r] = a4[r] * lrow[r] + s;
            mrow[r] = mnew;
            P[0][r] = p0; P[1][r] = p1;
        }
        if (a4[0] < 1.f || a4[1] < 1.f || a4[2] < 1.f || a4[3] < 1.f) {
#pragma unroll
            for (int dv = 0; dv < 8; ++dv)
#pragma unroll
                for (int r = 0; r < 4; ++r) O[dv][r] *= a4[r];
        }

        // P: C/D layout -> shared per-qhalf LDS -> A layout. Pair waves write
        // bit-identical values to the same addresses (benign); each wave
        // fences its own writes then reads.
#pragma unroll
        for (int kn = 0; kn < 2; ++kn)
#pragma unroll
            for (int r = 0; r < 4; ++r)
                Ps[qhalf][(quad * 4 + r) * 40 + kn * 16 + l16] = f2h(P[kn][r]);
        asm volatile("s_waitcnt lgkmcnt(0)" ::: "memory");

        const f16x8 af = *(const f16x8*)&Ps[qhalf][l16 * 40 + quad * 8];
#pragma unroll
        for (int dvt = 0; dvt < 8; ++dvt) {
            const f16x8 bf = *(const f16x8*)&Vs[(dvh * 128 + dvt * 16 + l16) * 40 + quad * 8];
            O[dvt] = MFMA_F16(af, bf, O[dvt], 0, 0, 0);
        }
        __syncthreads();
    }

    u16* __restrict__ Oz = Op + (size_t)z * 4194304;
#pragma unroll
    for (int r = 0; r < 4; ++r) {
        const float rl = 1.0f / lrow[r];
        const int grow = b * 2048 + q0 + qhalf * 16 + quad * 4 + r;
        const size_t rowoff = (size_t)grow * 256;
#pragma unroll
        for (int dvt = 0; dvt < 8; ++dvt)
            Oz[rowoff + dvh * 128 + dvt * 16 + l16] = f2h(O[dvt][r] * rl);
        if (dvh == 0 && l16 == 0) {
            lmp[z * 16384 + grow]         = lrow[r];
            lmp[32768 + z * 16384 + grow] = mrow[r];
        }
    }
}

// ---------------------------------------------------------------------------
// Kernel 4: combine + out projection + LayerNorm + LeakyReLU. (R6/R8 passing)
// ---------------------------------------------------------------------------
__global__ __launch_bounds__(256) void outproj_ln(
    const u16* __restrict__ Op, const float* __restrict__ lmp,
    const u16* __restrict__ Woh, const float* __restrict__ bo,
    const float* __restrict__ gamma, const float* __restrict__ beta,
    float* __restrict__ out)
{
    const int m0   = blockIdx.x * 64;
    const int t    = threadIdx.x;
    const int w    = t >> 6;
    const int lane = t & 63;
    const int quad = lane >> 4;
    const int l16  = lane & 15;

    __shared__ __align__(16) u16 Ls[64 * 40];
    __shared__ __align__(16) u16 Ws[256 * 40];
    __shared__ _Float16 w0s[64], w1s[64];

    if (t < 64) {
        const float l0 = lmp[m0 + t],          l1 = lmp[16384 + m0 + t];
        const float mm0 = lmp[32768 + m0 + t], mm1 = lmp[49152 + m0 + t];
        const float mm = fmaxf(mm0, mm1);
        const float u0 = l0 * __expf(mm0 - mm);
        const float u1 = l1 * __expf(mm1 - mm);
        const float inv = 1.0f / (u0 + u1);
        w0s[t] = (_Float16)(u0 * inv);
        w1s[t] = (_Float16)(u1 * inv);
    }
    __syncthreads();

    f32x4 acc[16];
#pragma unroll
    for (int i = 0; i < 16; ++i) acc[i] = f32x4{0.f, 0.f, 0.f, 0.f};

    for (int kc = 0; kc < 8; ++kc) {
        {
            const int row = t >> 2, cg = t & 3;
            const size_t off = (size_t)(m0 + row) * 256 + kc * 32 + cg * 8;
            const f16x8 o0 = __builtin_bit_cast(f16x8, *(const int4*)&Op[off]);
            const f16x8 o1 = __builtin_bit_cast(f16x8, *(const int4*)&Op[4194304 + off]);
            const _Float16 w0 = w0s[row], w1 = w1s[row];
            f16x8 lw;
#pragma unroll
            for (int j = 0; j < 8; ++j) lw[j] = o0[j] * w0 + o1[j] * w1;
            *(int4*)&Ls[row * 40 + cg * 8] = __builtin_bit_cast(int4, lw);
        }
#pragma unroll
        for (int i = 0; i < 4; ++i) {
            const int ch = i * 256 + t;
            const int row = ch >> 2, cg = ch & 3;
            *(int4*)&Ws[row * 40 + cg * 8] =
                *(const int4*)&Woh[(size_t)row * 256 + kc * 32 + cg * 8];
        }
        __syncthreads();

        const f16x8 af = *(const f16x8*)&Ls[(w * 16 + l16) * 40 + quad * 8];
#pragma unroll
        for (int nt = 0; nt < 16; ++nt) {
            const f16x8 bf = *(const f16x8*)&Ws[(nt * 16 + l16) * 40 + quad * 8];
            acc[nt] = MFMA_F16(af, bf, acc[nt], 0, 0, 0);
        }
        __syncthreads();
    }

    float g[16], bt[16], bb[16];
#pragma unroll
    for (int nt = 0; nt < 16; ++nt) {
        const int col = nt * 16 + l16;
        bb[nt] = bo[col]; g[nt] = gamma[col]; bt[nt] = beta[col];
    }

#pragma unroll
    for (int r = 0; r < 4; ++r) {
        float h[16];
        float sh = 0.f, sh2 = 0.f;
#pragma unroll
        for (int nt = 0; nt < 16; ++nt) {
            h[nt] = acc[nt][r] + bb[nt];
            sh  += h[nt];
            sh2 += h[nt] * h[nt];
        }
        sh  += __shfl_xor(sh, 1);  sh  += __shfl_xor(sh, 2);
        sh  += __shfl_xor(sh, 4);  sh  += __shfl_xor(sh, 8);
        sh2 += __shfl_xor(sh2, 1); sh2 += __shfl_xor(sh2, 2);
        sh2 += __shfl_xor(sh2, 4); sh2 += __shfl_xor(sh2, 8);
        const float mu  = sh * (1.f / 256.f);
        const float var = fmaxf(sh2 * (1.f / 256.f) - mu * mu, 0.f);
        const float rs  = rsqrtf(var + 1e-5f);
        const size_t row = (size_t)(m0 + w * 16 + quad * 4 + r) * 256;
#pragma unroll
        for (int nt = 0; nt < 16; ++nt) {
            const float hn = (h[nt] - mu) * rs * g[nt] + bt[nt];
            out[row + nt * 16 + l16] = (hn >= 0.f) ? hn : 0.01f * hn;
        }
    }
}

// ---------------------------------------------------------------------------
extern "C" void kernel_launch(void* const* d_in, const int* in_sizes, int n_in,
                              void* d_out, int out_size, void* d_ws, size_t ws_size,
                              hipStream_t stream)
{
    const float* x  = (const float*)d_in[0];
    const float* Wq = (const float*)d_in[1];
    const float* bq = (const float*)d_in[2];
    const float* Wk = (const float*)d_in[3];
    const float* bk = (const float*)d_in[4];
    const float* Wv = (const float*)d_in[5];
    const float* bv = (const float*)d_in[6];
    const float* Wo = (const float*)d_in[7];
    const float* bo = (const float*)d_in[8];
    const float* gm = (const float*)d_in[9];
    const float* bt = (const float*)d_in[10];
    float* out = (float*)d_out;

    // ws layout (u16 units). Op overlays dead V+xh regions:
    //   [W4 262144][Qh 4.19M][Kh 4.19M][Vt 4.19M][V 4.19M][xh 4.19M][lmp]
    u16* W4 = (u16*)d_ws;
    u16* Qh = W4 + 262144;
    u16* Kh = Qh + 4194304;
    u16* Vt = Kh + 4194304;
    u16* V  = Vt + 4194304;
    u16* xh = V  + 4194304;
    u16* Op = V;                          // 2 x 4194304 (overlays V, xh)
    float* lmp = (float*)(xh + 4194304);  // l[2][16384], m[2][16384]
    u16* Woh = W4 + 196608;

    prep       <<<2048,           256,        0, stream>>>(x, Wq, Wk, Wv, Wo, xh, W4);
    proj_qkv   <<<dim3(256, 3),   256,        0, stream>>>(xh, W4, bq, bk, bv, Qh, Kh, V);
    transpose_v<<<dim3(64, 8, 8), dim3(32,8), 0, stream>>>(V, Vt);
    attn       <<<dim3(64, 8, 2), 256,        0, stream>>>(Qh, Kh, Vt, Op, lmp);
    outproj_ln <<<256,            256,        0, stream>>>(Op, lmp, Woh, bo, gm, bt, out);
}

// Round 10
// 221.171 us; speedup vs baseline: 1.3434x; 1.2839x over previous
//
#include <hip/hip_runtime.h>

typedef unsigned short u16;
typedef __attribute__((ext_vector_type(8))) _Float16 f16x8;
typedef __attribute__((ext_vector_type(4))) float f32x4;

#define MFMA_F16 __builtin_amdgcn_mfma_f32_16x16x32_f16

static __device__ __forceinline__ u16 f2h(float f) {
    return __builtin_bit_cast(u16, (_Float16)f);
}
static __device__ __forceinline__ ushort4 f4_to_h4(const float4 v) {
    ushort4 r;
    r.x = f2h(v.x); r.y = f2h(v.y); r.z = f2h(v.z); r.w = f2h(v.w);
    return r;
}

// ---------------------------------------------------------------------------
// Kernel 0: prep — convert x and Wq/Wk/Wv/Wo fp32 -> fp16. (passing R6 code)
// ---------------------------------------------------------------------------
__global__ __launch_bounds__(256) void prep(
    const float* __restrict__ x,
    const float* __restrict__ wq, const float* __restrict__ wk,
    const float* __restrict__ wv, const float* __restrict__ wo,
    u16* __restrict__ xh, u16* __restrict__ w4)
{
    const int tid = blockIdx.x * 256 + threadIdx.x;
    for (int i = tid; i < 1048576; i += 2048 * 256)
        ((ushort4*)xh)[i] = f4_to_h4(((const float4*)x)[i]);
    if (blockIdx.x < 64) {
        for (int i = tid; i < 65536; i += 16384) {
            const float* src = (i < 16384) ? wq : (i < 32768) ? wk
                             : (i < 49152) ? wv : wo;
            ((ushort4*)w4)[i] = f4_to_h4(((const float4*)src)[i & 16383]);
        }
    }
}

// ---------------------------------------------------------------------------
// Kernel 1: Q/K/V projection, fp16. (passing R6 code, unchanged)
// ---------------------------------------------------------------------------
__global__ __launch_bounds__(256) void proj_qkv(
    const u16* __restrict__ xh, const u16* __restrict__ w4,
    const float* __restrict__ bq, const float* __restrict__ bk,
    const float* __restrict__ bv,
    u16* __restrict__ Qh, u16* __restrict__ Kh, u16* __restrict__ V)
{
    const int z = blockIdx.y;
    const u16* __restrict__ W     = w4 + z * 65536;
    const float* __restrict__ bias = (z == 0) ? bq : (z == 1) ? bk : bv;
    u16* __restrict__ Y            = (z == 0) ? Qh : (z == 1) ? Kh : V;

    const int m0   = blockIdx.x * 64;
    const int t    = threadIdx.x;
    const int w    = t >> 6;
    const int lane = t & 63;
    const int quad = lane >> 4;
    const int l16  = lane & 15;

    __shared__ __align__(16) u16 Xs[64 * 40];
    __shared__ __align__(16) u16 Ws[256 * 40];

    f32x4 acc[16];
#pragma unroll
    for (int i = 0; i < 16; ++i) acc[i] = f32x4{0.f, 0.f, 0.f, 0.f};

    for (int kc = 0; kc < 8; ++kc) {
        {
            const int row = t >> 2, cg = t & 3;
            *(int4*)&Xs[row * 40 + cg * 8] =
                *(const int4*)&xh[(size_t)(m0 + row) * 256 + kc * 32 + cg * 8];
        }
#pragma unroll
        for (int i = 0; i < 4; ++i) {
            const int ch = i * 256 + t;
            const int row = ch >> 2, cg = ch & 3;
            *(int4*)&Ws[row * 40 + cg * 8] =
                *(const int4*)&W[(size_t)row * 256 + kc * 32 + cg * 8];
        }
        __syncthreads();

        const f16x8 af = *(const f16x8*)&Xs[(w * 16 + l16) * 40 + quad * 8];
#pragma unroll
        for (int nt = 0; nt < 16; ++nt) {
            const f16x8 bf = *(const f16x8*)&Ws[(nt * 16 + l16) * 40 + quad * 8];
            acc[nt] = MFMA_F16(af, bf, acc[nt], 0, 0, 0);
        }
        __syncthreads();
    }

#pragma unroll
    for (int nt = 0; nt < 16; ++nt) {
        const int col = nt * 16 + l16;
        const float bb = bias[col];
#pragma unroll
        for (int r = 0; r < 4; ++r) {
            const int row = m0 + w * 16 + quad * 4 + r;
            Y[(size_t)row * 256 + col] = f2h(acc[nt][r] + bb);
        }
    }
}

// ---------------------------------------------------------------------------
// Kernel 2: per-batch transpose V[b][n][d] -> Vt[b][d][n]   (fp16)
// ---------------------------------------------------------------------------
__global__ __launch_bounds__(256) void transpose_v(
    const u16* __restrict__ V, u16* __restrict__ Vt)
{
    __shared__ u16 tile[32][33];
    const int b  = blockIdx.z;
    const int n0 = blockIdx.x * 32;
    const int d0 = blockIdx.y * 32;
    const int tx = threadIdx.x;
    const int ty = threadIdx.y;
#pragma unroll
    for (int i = 0; i < 4; ++i)
        tile[ty + 8 * i][tx] =
            V[(size_t)(b * 2048 + n0 + ty + 8 * i) * 256 + d0 + tx];
    __syncthreads();
#pragma unroll
    for (int i = 0; i < 4; ++i)
        Vt[(size_t)b * 524288 + (size_t)(d0 + ty + 8 * i) * 2048 + n0 + tx] =
            tile[tx][ty + 8 * i];
}

// ---------------------------------------------------------------------------
// Kernel 3: flash attention, fp16, split-K x nz (nz = gridDim.z, 2..4).
// R6 structure: 64 q/block, 4 waves x 16 q, O[16], KT=32, immediate softmax,
// NO prefetch, NO wave duplication. LDS = Ks + Vs only (37376 B -> 4 blk/CU):
// P lives in Vs's per-row pad slabs (cols 32..39, never touched by staging).
//   P(w, qr, k) at Vs[((w*16+qr)*4 + (k>>3))*40 + 32 + (k&7)]
//   A-frag read: b128 at Vs[((w*16+l16)*4 + quad)*40 + 32]  (16B-aligned)
// ---------------------------------------------------------------------------
__global__ __launch_bounds__(256) void attn(
    const u16* __restrict__ Qh, const u16* __restrict__ Kg,
    const u16* __restrict__ Vt, u16* __restrict__ Op, float* __restrict__ lmp)
{
    const int nz = gridDim.z;
    const int z  = blockIdx.z;
    const int tbase = 64 / nz, trem = 64 % nz;
    const int my_tiles = tbase + (z < trem ? 1 : 0);
    const int tile0    = tbase * z + (z < trem ? z : trem);

    const int b  = blockIdx.y;
    const int q0 = blockIdx.x * 64;
    const int t    = threadIdx.x;
    const int w    = t >> 6;
    const int lane = t & 63;
    const int quad = lane >> 4;
    const int l16  = lane & 15;

    __shared__ __align__(16) u16 Ks[32 * 264];   // 32 keys x 256 (+8 pad)
    __shared__ __align__(16) u16 Vs[256 * 40];   // 256 dv x 32 keys (+8 pad=P)

    f16x8 qf[8];
    {
        const size_t qrow = (size_t)(b * 2048 + q0 + w * 16 + l16) * 256;
#pragma unroll
        for (int kc = 0; kc < 8; ++kc)
            qf[kc] = *(const f16x8*)&Qh[qrow + kc * 32 + quad * 8];
    }

    f32x4 O[16];
#pragma unroll
    for (int i = 0; i < 16; ++i) O[i] = f32x4{0.f, 0.f, 0.f, 0.f};
    float mrow[4], lrow[4];
#pragma unroll
    for (int r = 0; r < 4; ++r) { mrow[r] = -1e30f; lrow[r] = 0.f; }

    for (int it = 0; it < my_tiles; ++it) {
        const int kt = (tile0 + it) * 32;   // absolute key offset in [0,2048)
        // stage K tile: 1024 int4-chunks, 4/thread
#pragma unroll
        for (int i = 0; i < 4; ++i) {
            const int ch = i * 256 + t;
            const int row = ch >> 5, cg = ch & 31;
            *(int4*)&Ks[row * 264 + cg * 8] =
                *(const int4*)&Kg[(size_t)(b * 2048 + kt + row) * 256 + cg * 8];
        }
        // stage Vt tile: 1024 int4-chunks, 4/thread (cols 0..31 only)
#pragma unroll
        for (int i = 0; i < 4; ++i) {
            const int ch = i * 256 + t;
            const int row = ch >> 2, cg = ch & 3;
            *(int4*)&Vs[row * 40 + cg * 8] =
                *(const int4*)&Vt[(size_t)b * 524288 + (size_t)row * 2048 + kt + cg * 8];
        }
        __syncthreads();

        f32x4 S[2];
        S[0] = f32x4{0.f, 0.f, 0.f, 0.f};
        S[1] = f32x4{0.f, 0.f, 0.f, 0.f};
#pragma unroll
        for (int kc = 0; kc < 8; ++kc) {
#pragma unroll
            for (int kn = 0; kn < 2; ++kn) {
                const f16x8 bf = *(const f16x8*)&Ks[(kn * 16 + l16) * 264 + kc * 32 + quad * 8];
                S[kn] = MFMA_F16(qf[kc], bf, S[kn], 0, 0, 0);
            }
        }

        // online softmax (immediate form; rows quad*4+r across 16 lanes)
        float P[2][4], a4[4];
#pragma unroll
        for (int r = 0; r < 4; ++r) {
            float mt = fmaxf(S[0][r], S[1][r]);
            mt = fmaxf(mt, __shfl_xor(mt, 1));
            mt = fmaxf(mt, __shfl_xor(mt, 2));
            mt = fmaxf(mt, __shfl_xor(mt, 4));
            mt = fmaxf(mt, __shfl_xor(mt, 8));
            const float mnew = fmaxf(mrow[r], mt);
            a4[r] = __expf(mrow[r] - mnew);
            const float p0 = __expf(S[0][r] - mnew);
            const float p1 = __expf(S[1][r] - mnew);
            float s = p0 + p1;
            s += __shfl_xor(s, 1);
            s += __shfl_xor(s, 2);
            s += __shfl_xor(s, 4);
            s += __shfl_xor(s, 8);
            lrow[r] = a4[r] * lrow[r] + s;
            mrow[r] = mnew;
            P[0][r] = p0; P[1][r] = p1;
        }
        if (a4[0] < 1.f || a4[1] < 1.f || a4[2] < 1.f || a4[3] < 1.f) {
#pragma unroll
            for (int dv = 0; dv < 16; ++dv)
#pragma unroll
                for (int r = 0; r < 4; ++r) O[dv][r] *= a4[r];
        }

        // P: C/D layout -> Vs pad slabs -> A layout (wave-local fence)
#pragma unroll
        for (int kn = 0; kn < 2; ++kn)
#pragma unroll
            for (int r = 0; r < 4; ++r)
                Vs[((w * 16 + quad * 4 + r) * 4 + kn * 2 + (l16 >> 3)) * 40
                   + 32 + (l16 & 7)] = f2h(P[kn][r]);
        asm volatile("s_waitcnt lgkmcnt(0)" ::: "memory");

        const f16x8 af = *(const f16x8*)&Vs[((w * 16 + l16) * 4 + quad) * 40 + 32];
#pragma unroll
        for (int dv = 0; dv < 16; ++dv) {
            const f16x8 bf = *(const f16x8*)&Vs[(dv * 16 + l16) * 40 + quad * 8];
            O[dv] = MFMA_F16(af, bf, O[dv], 0, 0, 0);
        }
        __syncthreads();
    }

    u16* __restrict__ Oz = Op + (size_t)z * 4194304;
#pragma unroll
    for (int r = 0; r < 4; ++r) {
        const float rl = 1.0f / lrow[r];
        const int grow = b * 2048 + q0 + w * 16 + quad * 4 + r;
        const size_t rowoff = (size_t)grow * 256;
#pragma unroll
        for (int dv = 0; dv < 16; ++dv)
            Oz[rowoff + dv * 16 + l16] = f2h(O[dv][r] * rl);
        if (l16 == 0) {
            lmp[z * 16384 + grow]        = lrow[r];
            lmp[(nz + z) * 16384 + grow] = mrow[r];
        }
    }
}

// ---------------------------------------------------------------------------
// Kernel 4: combine nz partials + out projection + LayerNorm + LeakyReLU.
// Fixed 4-iteration combine (zi = zz<nz ? zz : 0, weight 0 beyond nz) keeps
// the partial loads ILP'd and in-bounds for any nz in {2,3,4}.
// ---------------------------------------------------------------------------
__global__ __launch_bounds__(256) void outproj_ln(
    const u16* __restrict__ Op, const float* __restrict__ lmp,
    const u16* __restrict__ Woh, const float* __restrict__ bo,
    const float* __restrict__ gamma, const float* __restrict__ beta,
    float* __restrict__ out, int nz)
{
    const int m0   = blockIdx.x * 64;
    const int t    = threadIdx.x;
    const int w    = t >> 6;
    const int lane = t & 63;
    const int quad = lane >> 4;
    const int l16  = lane & 15;

    __shared__ __align__(16) u16 Ls[64 * 40];
    __shared__ __align__(16) u16 Ws[256 * 40];
    __shared__ _Float16 wcs[4][64];

    if (t < 64) {
        float mm = -1e30f;
        for (int zz = 0; zz < nz; ++zz)
            mm = fmaxf(mm, lmp[(nz + zz) * 16384 + m0 + t]);
        float u[4] = {0.f, 0.f, 0.f, 0.f}, s = 0.f;
        for (int zz = 0; zz < nz; ++zz) {
            u[zz] = lmp[zz * 16384 + m0 + t] * __expf(lmp[(nz + zz) * 16384 + m0 + t] - mm);
            s += u[zz];
        }
        const float inv = 1.0f / s;
#pragma unroll
        for (int zz = 0; zz < 4; ++zz)
            wcs[zz][t] = (_Float16)((zz < nz ? u[zz] : 0.f) * inv);
    }
    __syncthreads();

    f32x4 acc[16];
#pragma unroll
    for (int i = 0; i < 16; ++i) acc[i] = f32x4{0.f, 0.f, 0.f, 0.f};

    for (int kc = 0; kc < 8; ++kc) {
        {
            const int row = t >> 2, cg = t & 3;
            const size_t off = (size_t)(m0 + row) * 256 + kc * 32 + cg * 8;
            f16x8 lw;
#pragma unroll
            for (int j = 0; j < 8; ++j) lw[j] = (_Float16)0;
#pragma unroll
            for (int zz = 0; zz < 4; ++zz) {
                const int zi = (zz < nz) ? zz : 0;
                const f16x8 o = __builtin_bit_cast(f16x8,
                    *(const int4*)&Op[(size_t)zi * 4194304 + off]);
                const _Float16 wz = wcs[zz][row];
#pragma unroll
                for (int j = 0; j < 8; ++j) lw[j] += o[j] * wz;
            }
            *(int4*)&Ls[row * 40 + cg * 8] = __builtin_bit_cast(int4, lw);
        }
#pragma unroll
        for (int i = 0; i < 4; ++i) {
            const int ch = i * 256 + t;
            const int row = ch >> 2, cg = ch & 3;
            *(int4*)&Ws[row * 40 + cg * 8] =
                *(const int4*)&Woh[(size_t)row * 256 + kc * 32 + cg * 8];
        }
        __syncthreads();

        const f16x8 af = *(const f16x8*)&Ls[(w * 16 + l16) * 40 + quad * 8];
#pragma unroll
        for (int nt = 0; nt < 16; ++nt) {
            const f16x8 bf = *(const f16x8*)&Ws[(nt * 16 + l16) * 40 + quad * 8];
            acc[nt] = MFMA_F16(af, bf, acc[nt], 0, 0, 0);
        }
        __syncthreads();
    }

    float g[16], bt[16], bb[16];
#pragma unroll
    for (int nt = 0; nt < 16; ++nt) {
        const int col = nt * 16 + l16;
        bb[nt] = bo[col]; g[nt] = gamma[col]; bt[nt] = beta[col];
    }

#pragma unroll
    for (int r = 0; r < 4; ++r) {
        float h[16];
        float sh = 0.f, sh2 = 0.f;
#pragma unroll
        for (int nt = 0; nt < 16; ++nt) {
            h[nt] = acc[nt][r] + bb[nt];
            sh  += h[nt];
            sh2 += h[nt] * h[nt];
        }
        sh  += __shfl_xor(sh, 1);  sh  += __shfl_xor(sh, 2);
        sh  += __shfl_xor(sh, 4);  sh  += __shfl_xor(sh, 8);
        sh2 += __shfl_xor(sh2, 1); sh2 += __shfl_xor(sh2, 2);
        sh2 += __shfl_xor(sh2, 4); sh2 += __shfl_xor(sh2, 8);
        const float mu  = sh * (1.f / 256.f);
        const float var = fmaxf(sh2 * (1.f / 256.f) - mu * mu, 0.f);
        const float rs  = rsqrtf(var + 1e-5f);
        const size_t row = (size_t)(m0 + w * 16 + quad * 4 + r) * 256;
#pragma unroll
        for (int nt = 0; nt < 16; ++nt) {
            const float hn = (h[nt] - mu) * rs * g[nt] + bt[nt];
            out[row + nt * 16 + l16] = (hn >= 0.f) ? hn : 0.01f * hn;
        }
    }
}

// ---------------------------------------------------------------------------
extern "C" void kernel_launch(void* const* d_in, const int* in_sizes, int n_in,
                              void* d_out, int out_size, void* d_ws, size_t ws_size,
                              hipStream_t stream)
{
    const float* x  = (const float*)d_in[0];
    const float* Wq = (const float*)d_in[1];
    const float* bq = (const float*)d_in[2];
    const float* Wk = (const float*)d_in[3];
    const float* bk = (const float*)d_in[4];
    const float* Wv = (const float*)d_in[5];
    const float* bv = (const float*)d_in[6];
    const float* Wo = (const float*)d_in[7];
    const float* bo = (const float*)d_in[8];
    const float* gm = (const float*)d_in[9];
    const float* bt = (const float*)d_in[10];
    float* out = (float*)d_out;

    // ws layout (u16): [W4][Qh][Kh][Vt][V][xh][Op extras][lmp]
    //   Op = nz contiguous partials starting at V (V,xh dead by attn time).
    //   nz chosen from ws_size:  nz=4 needs ~59.8 MB, nz=3 ~51.3, nz=2 ~42.8.
    const size_t BASE_U16 = 262144u + 5u * 4194304u;
    const size_t need4 = (BASE_U16 + 2u * 4194304u) * 2 + 4u * 2u * 16384u * 4u;
    const size_t need3 = (BASE_U16 + 1u * 4194304u) * 2 + 3u * 2u * 16384u * 4u;
    int nz = (ws_size >= need4) ? 4 : (ws_size >= need3) ? 3 : 2;

    u16* W4 = (u16*)d_ws;
    u16* Qh = W4 + 262144;
    u16* Kh = Qh + 4194304;
    u16* Vt = Kh + 4194304;
    u16* V  = Vt + 4194304;
    u16* xh = V  + 4194304;
    u16* Op = V;
    float* lmp = (float*)(xh + 4194304 + (size_t)(nz > 2 ? nz - 2 : 0) * 4194304);
    u16* Woh = W4 + 196608;

    prep       <<<2048,            256,        0, stream>>>(x, Wq, Wk, Wv, Wo, xh, W4);
    proj_qkv   <<<dim3(256, 3),    256,        0, stream>>>(xh, W4, bq, bk, bv, Qh, Kh, V);
    transpose_v<<<dim3(64, 8, 8),  dim3(32,8), 0, stream>>>(V, Vt);
    attn       <<<dim3(32, 8, nz), 256,        0, stream>>>(Qh, Kh, Vt, Op, lmp);
    outproj_ln <<<256,             256,        0, stream>>>(Op, lmp, Woh, bo, gm, bt, out, nz);
}

// Round 11
// 203.697 us; speedup vs baseline: 1.4586x; 1.0858x over previous
//
#include <hip/hip_runtime.h>

typedef unsigned short u16;
typedef __attribute__((ext_vector_type(8))) _Float16 f16x8;
typedef __attribute__((ext_vector_type(4))) float f32x4;

#define MFMA_F16 __builtin_amdgcn_mfma_f32_16x16x32_f16

static __device__ __forceinline__ u16 f2h(float f) {
    return __builtin_bit_cast(u16, (_Float16)f);
}
static __device__ __forceinline__ ushort4 f4_to_h4(const float4 v) {
    ushort4 r;
    r.x = f2h(v.x); r.y = f2h(v.y); r.z = f2h(v.z); r.w = f2h(v.w);
    return r;
}

// ---------------------------------------------------------------------------
// Kernel 0: prep — convert x and Wq/Wk/Wv/Wo fp32 -> fp16. (passing R10)
// ---------------------------------------------------------------------------
__global__ __launch_bounds__(256) void prep(
    const float* __restrict__ x,
    const float* __restrict__ wq, const float* __restrict__ wk,
    const float* __restrict__ wv, const float* __restrict__ wo,
    u16* __restrict__ xh, u16* __restrict__ w4)
{
    const int tid = blockIdx.x * 256 + threadIdx.x;
    for (int i = tid; i < 1048576; i += 2048 * 256)
        ((ushort4*)xh)[i] = f4_to_h4(((const float4*)x)[i]);
    if (blockIdx.x < 64) {
        for (int i = tid; i < 65536; i += 16384) {
            const float* src = (i < 16384) ? wq : (i < 32768) ? wk
                             : (i < 49152) ? wv : wo;
            ((ushort4*)w4)[i] = f4_to_h4(((const float4*)src)[i & 16383]);
        }
    }
}

// ---------------------------------------------------------------------------
// Kernel 1: Q/K/V projection, fp16. (passing R10, unchanged)
// ---------------------------------------------------------------------------
__global__ __launch_bounds__(256) void proj_qkv(
    const u16* __restrict__ xh, const u16* __restrict__ w4,
    const float* __restrict__ bq, const float* __restrict__ bk,
    const float* __restrict__ bv,
    u16* __restrict__ Qh, u16* __restrict__ Kh, u16* __restrict__ V)
{
    const int z = blockIdx.y;
    const u16* __restrict__ W     = w4 + z * 65536;
    const float* __restrict__ bias = (z == 0) ? bq : (z == 1) ? bk : bv;
    u16* __restrict__ Y            = (z == 0) ? Qh : (z == 1) ? Kh : V;

    const int m0   = blockIdx.x * 64;
    const int t    = threadIdx.x;
    const int w    = t >> 6;
    const int lane = t & 63;
    const int quad = lane >> 4;
    const int l16  = lane & 15;

    __shared__ __align__(16) u16 Xs[64 * 40];
    __shared__ __align__(16) u16 Ws[256 * 40];

    f32x4 acc[16];
#pragma unroll
    for (int i = 0; i < 16; ++i) acc[i] = f32x4{0.f, 0.f, 0.f, 0.f};

    for (int kc = 0; kc < 8; ++kc) {
        {
            const int row = t >> 2, cg = t & 3;
            *(int4*)&Xs[row * 40 + cg * 8] =
                *(const int4*)&xh[(size_t)(m0 + row) * 256 + kc * 32 + cg * 8];
        }
#pragma unroll
        for (int i = 0; i < 4; ++i) {
            const int ch = i * 256 + t;
            const int row = ch >> 2, cg = ch & 3;
            *(int4*)&Ws[row * 40 + cg * 8] =
                *(const int4*)&W[(size_t)row * 256 + kc * 32 + cg * 8];
        }
        __syncthreads();

        const f16x8 af = *(const f16x8*)&Xs[(w * 16 + l16) * 40 + quad * 8];
#pragma unroll
        for (int nt = 0; nt < 16; ++nt) {
            const f16x8 bf = *(const f16x8*)&Ws[(nt * 16 + l16) * 40 + quad * 8];
            acc[nt] = MFMA_F16(af, bf, acc[nt], 0, 0, 0);
        }
        __syncthreads();
    }

#pragma unroll
    for (int nt = 0; nt < 16; ++nt) {
        const int col = nt * 16 + l16;
        const float bb = bias[col];
#pragma unroll
        for (int r = 0; r < 4; ++r) {
            const int row = m0 + w * 16 + quad * 4 + r;
            Y[(size_t)row * 256 + col] = f2h(acc[nt][r] + bb);
        }
    }
}

// ---------------------------------------------------------------------------
// Kernel 2: per-batch transpose V[b][n][d] -> Vt[b][d][n]   (fp16)
// ---------------------------------------------------------------------------
__global__ __launch_bounds__(256) void transpose_v(
    const u16* __restrict__ V, u16* __restrict__ Vt)
{
    __shared__ u16 tile[32][33];
    const int b  = blockIdx.z;
    const int n0 = blockIdx.x * 32;
    const int d0 = blockIdx.y * 32;
    const int tx = threadIdx.x;
    const int ty = threadIdx.y;
#pragma unroll
    for (int i = 0; i < 4; ++i)
        tile[ty + 8 * i][tx] =
            V[(size_t)(b * 2048 + n0 + ty + 8 * i) * 256 + d0 + tx];
    __syncthreads();
#pragma unroll
    for (int i = 0; i < 4; ++i)
        Vt[(size_t)b * 524288 + (size_t)(d0 + ty + 8 * i) * 2048 + n0 + tx] =
            tile[tx][ty + 8 * i];
}

// ---------------------------------------------------------------------------
// Kernel 3: flash attention, TRANSPOSED scores: S^T = K Q^T, O^T = V^T P^T.
//   - q lives in lanes (l16), keys in regs -> softmax: in-lane 8-reduce +
//     2 shuffles (xor16/xor32 across quads). No P LDS round-trip: P packs
//     directly into the PV B-operand fragment.
//   - K staged with row permutation perm(m)=((m>>2)&3)*8+(m>>4)*4+(m&3) so
//     lane's S^T keys come out contiguous (quad*8+j); V staging is identity
//     (phys key = kt + B-frag k-index — verified algebraically).
//   - Epilogue: O^T -> LDS (Ks/Vs dead, 33.8KB) -> coalesced global store.
// split-K x nz as R10. LDS 37376 B. No prefetch.
// ---------------------------------------------------------------------------
__global__ __launch_bounds__(256) void attn(
    const u16* __restrict__ Qh, const u16* __restrict__ Kg,
    const u16* __restrict__ Vt, u16* __restrict__ Op, float* __restrict__ lmp)
{
    const int nz = gridDim.z;
    const int z  = blockIdx.z;
    const int tbase = 64 / nz, trem = 64 % nz;
    const int my_tiles = tbase + (z < trem ? 1 : 0);
    const int tile0    = tbase * z + (z < trem ? z : trem);

    const int b  = blockIdx.y;
    const int q0 = blockIdx.x * 64;
    const int t    = threadIdx.x;
    const int w    = t >> 6;
    const int lane = t & 63;
    const int quad = lane >> 4;
    const int l16  = lane & 15;

    __shared__ __align__(16) u16 smem[18688];   // 37376 B
    u16* Ks = smem;                // 32 x 264 (stride-pad 8)
    u16* Vs = smem + 8448;         // 256 x 40 (stride-pad 8)
    u16* Os = smem;                // epilogue reuse: 64 x 264

    f16x8 qf[8];   // B-operand: n=q=l16, k=quad*8+j (feature dim)
    {
        const size_t qrow = (size_t)(b * 2048 + q0 + w * 16 + l16) * 256;
#pragma unroll
        for (int kc = 0; kc < 8; ++kc)
            qf[kc] = *(const f16x8*)&Qh[qrow + kc * 32 + quad * 8];
    }

    f32x4 O[16];   // O^T: reg r -> dv = dvt*16+quad*4+r, lane l16 -> q
#pragma unroll
    for (int i = 0; i < 16; ++i) O[i] = f32x4{0.f, 0.f, 0.f, 0.f};
    float mrow = -1e30f, lrow = 0.f;   // per-lane (q = l16)

    for (int it = 0; it < my_tiles; ++it) {
        const int kt = (tile0 + it) * 32;
        // stage K tile with row permutation: LDS row m <- phys key kt+perm(m)
#pragma unroll
        for (int i = 0; i < 4; ++i) {
            const int ch = i * 256 + t;
            const int row = ch >> 5, cg = ch & 31;
            const int prow = ((row >> 2) & 3) * 8 + (row >> 4) * 4 + (row & 3);
            *(int4*)&Ks[row * 264 + cg * 8] =
                *(const int4*)&Kg[(size_t)(b * 2048 + kt + prow) * 256 + cg * 8];
        }
        // stage Vt tile (identity layout): 1024 int4-chunks
#pragma unroll
        for (int i = 0; i < 4; ++i) {
            const int ch = i * 256 + t;
            const int row = ch >> 2, cg = ch & 3;
            *(int4*)&Vs[row * 40 + cg * 8] =
                *(const int4*)&Vt[(size_t)b * 524288 + (size_t)row * 2048 + kt + cg * 8];
        }
        __syncthreads();

        // S^T = K Q^T : A = K (m=key), B = Q (n=q). 2 m-tiles x 8 kc.
        f32x4 S[2];
        S[0] = f32x4{0.f, 0.f, 0.f, 0.f};
        S[1] = f32x4{0.f, 0.f, 0.f, 0.f};
#pragma unroll
        for (int kc = 0; kc < 8; ++kc) {
#pragma unroll
            for (int kn = 0; kn < 2; ++kn) {
                const f16x8 kf = *(const f16x8*)&Ks[(kn * 16 + l16) * 264 + kc * 32 + quad * 8];
                S[kn] = MFMA_F16(kf, qf[kc], S[kn], 0, 0, 0);
            }
        }
        // lane holds S^T[key = kt + quad*8 + kn*4 + r][q = q0 + w*16 + l16]

        // softmax: reduce over this lane's 8 keys, then across quads
        float mt = fmaxf(fmaxf(fmaxf(S[0][0], S[0][1]), fmaxf(S[0][2], S[0][3])),
                         fmaxf(fmaxf(S[1][0], S[1][1]), fmaxf(S[1][2], S[1][3])));
        mt = fmaxf(mt, __shfl_xor(mt, 16));
        mt = fmaxf(mt, __shfl_xor(mt, 32));
        const float mnew = fmaxf(mrow, mt);
        const float a = __expf(mrow - mnew);
        float p[2][4];
        float s = 0.f;
#pragma unroll
        for (int kn = 0; kn < 2; ++kn)
#pragma unroll
            for (int r = 0; r < 4; ++r) {
                p[kn][r] = __expf(S[kn][r] - mnew);
                s += p[kn][r];
            }
        s += __shfl_xor(s, 16);
        s += __shfl_xor(s, 32);
        lrow = a * lrow + s;
        mrow = mnew;

        if (__any(a < 1.f)) {
#pragma unroll
            for (int dv = 0; dv < 16; ++dv)
#pragma unroll
                for (int r = 0; r < 4; ++r) O[dv][r] *= a;
        }

        // pack P directly into PV B-operand fragment: j = kn*4 + r
        f16x8 pf;
#pragma unroll
        for (int kn = 0; kn < 2; ++kn)
#pragma unroll
            for (int r = 0; r < 4; ++r)
                pf[kn * 4 + r] = (_Float16)p[kn][r];

        // O^T += V^T P^T : A = V^T (m=dv), B = P (n=q), contract 32 keys
#pragma unroll
        for (int dvt = 0; dvt < 16; ++dvt) {
            const f16x8 vf = *(const f16x8*)&Vs[(dvt * 16 + l16) * 40 + quad * 8];
            O[dvt] = MFMA_F16(vf, pf, O[dvt], 0, 0, 0);
        }
        __syncthreads();
    }

    // epilogue: normalize, O^T -> LDS transpose -> coalesced store
    {
        const float rl = 1.0f / lrow;
#pragma unroll
        for (int dvt = 0; dvt < 16; ++dvt) {
            ushort4 h4;
            h4.x = f2h(O[dvt][0] * rl);
            h4.y = f2h(O[dvt][1] * rl);
            h4.z = f2h(O[dvt][2] * rl);
            h4.w = f2h(O[dvt][3] * rl);
            *(ushort4*)&Os[(w * 16 + l16) * 264 + dvt * 16 + quad * 4] = h4;
        }
        if (quad == 0) {
            const int grow = b * 2048 + q0 + w * 16 + l16;
            lmp[z * 16384 + grow]        = lrow;
            lmp[(nz + z) * 16384 + grow] = mrow;
        }
    }
    __syncthreads();

    u16* __restrict__ Oz = Op + (size_t)z * 4194304;
    {
        const int row = t >> 2;
#pragma unroll
        for (int i = 0; i < 8; ++i) {
            const int chunk = (t & 3) * 8 + i;       // 0..31
            *(int4*)&Oz[(size_t)(b * 2048 + q0 + row) * 256 + chunk * 8] =
                *(const int4*)&Os[row * 264 + chunk * 8];
        }
    }
}

// ---------------------------------------------------------------------------
// Kernel 4: combine nz partials + out projection + LayerNorm + LeakyReLU.
// (passing R10, unchanged)
// ---------------------------------------------------------------------------
__global__ __launch_bounds__(256) void outproj_ln(
    const u16* __restrict__ Op, const float* __restrict__ lmp,
    const u16* __restrict__ Woh, const float* __restrict__ bo,
    const float* __restrict__ gamma, const float* __restrict__ beta,
    float* __restrict__ out, int nz)
{
    const int m0   = blockIdx.x * 64;
    const int t    = threadIdx.x;
    const int w    = t >> 6;
    const int lane = t & 63;
    const int quad = lane >> 4;
    const int l16  = lane & 15;

    __shared__ __align__(16) u16 Ls[64 * 40];
    __shared__ __align__(16) u16 Ws[256 * 40];
    __shared__ _Float16 wcs[4][64];

    if (t < 64) {
        float mm = -1e30f;
        for (int zz = 0; zz < nz; ++zz)
            mm = fmaxf(mm, lmp[(nz + zz) * 16384 + m0 + t]);
        float u[4] = {0.f, 0.f, 0.f, 0.f}, s = 0.f;
        for (int zz = 0; zz < nz; ++zz) {
            u[zz] = lmp[zz * 16384 + m0 + t] * __expf(lmp[(nz + zz) * 16384 + m0 + t] - mm);
            s += u[zz];
        }
        const float inv = 1.0f / s;
#pragma unroll
        for (int zz = 0; zz < 4; ++zz)
            wcs[zz][t] = (_Float16)((zz < nz ? u[zz] : 0.f) * inv);
    }
    __syncthreads();

    f32x4 acc[16];
#pragma unroll
    for (int i = 0; i < 16; ++i) acc[i] = f32x4{0.f, 0.f, 0.f, 0.f};

    for (int kc = 0; kc < 8; ++kc) {
        {
            const int row = t >> 2, cg = t & 3;
            const size_t off = (size_t)(m0 + row) * 256 + kc * 32 + cg * 8;
            f16x8 lw;
#pragma unroll
            for (int j = 0; j < 8; ++j) lw[j] = (_Float16)0;
#pragma unroll
            for (int zz = 0; zz < 4; ++zz) {
                const int zi = (zz < nz) ? zz : 0;
                const f16x8 o = __builtin_bit_cast(f16x8,
                    *(const int4*)&Op[(size_t)zi * 4194304 + off]);
                const _Float16 wz = wcs[zz][row];
#pragma unroll
                for (int j = 0; j < 8; ++j) lw[j] += o[j] * wz;
            }
            *(int4*)&Ls[row * 40 + cg * 8] = __builtin_bit_cast(int4, lw);
        }
#pragma unroll
        for (int i = 0; i < 4; ++i) {
            const int ch = i * 256 + t;
            const int row = ch >> 2, cg = ch & 3;
            *(int4*)&Ws[row * 40 + cg * 8] =
                *(const int4*)&Woh[(size_t)row * 256 + kc * 32 + cg * 8];
        }
        __syncthreads();

        const f16x8 af = *(const f16x8*)&Ls[(w * 16 + l16) * 40 + quad * 8];
#pragma unroll
        for (int nt = 0; nt < 16; ++nt) {
            const f16x8 bf = *(const f16x8*)&Ws[(nt * 16 + l16) * 40 + quad * 8];
            acc[nt] = MFMA_F16(af, bf, acc[nt], 0, 0, 0);
        }
        __syncthreads();
    }

    float g[16], bt[16], bb[16];
#pragma unroll
    for (int nt = 0; nt < 16; ++nt) {
        const int col = nt * 16 + l16;
        bb[nt] = bo[col]; g[nt] = gamma[col]; bt[nt] = beta[col];
    }

#pragma unroll
    for (int r = 0; r < 4; ++r) {
        float h[16];
        float sh = 0.f, sh2 = 0.f;
#pragma unroll
        for (int nt = 0; nt < 16; ++nt) {
            h[nt] = acc[nt][r] + bb[nt];
            sh  += h[nt];
            sh2 += h[nt] * h[nt];
        }
        sh  += __shfl_xor(sh, 1);  sh  += __shfl_xor(sh, 2);
        sh  += __shfl_xor(sh, 4);  sh  += __shfl_xor(sh, 8);
        sh2 += __shfl_xor(sh2, 1); sh2 += __shfl_xor(sh2, 2);
        sh2 += __shfl_xor(sh2, 4); sh2 += __shfl_xor(sh2, 8);
        const float mu  = sh * (1.f / 256.f);
        const float var = fmaxf(sh2 * (1.f / 256.f) - mu * mu, 0.f);
        const float rs  = rsqrtf(var + 1e-5f);
        const size_t row = (size_t)(m0 + w * 16 + quad * 4 + r) * 256;
#pragma unroll
        for (int nt = 0; nt < 16; ++nt) {
            const float hn = (h[nt] - mu) * rs * g[nt] + bt[nt];
            out[row + nt * 16 + l16] = (hn >= 0.f) ? hn : 0.01f * hn;
        }
    }
}

// ---------------------------------------------------------------------------
extern "C" void kernel_launch(void* const* d_in, const int* in_sizes, int n_in,
                              void* d_out, int out_size, void* d_ws, size_t ws_size,
                              hipStream_t stream)
{
    const float* x  = (const float*)d_in[0];
    const float* Wq = (const float*)d_in[1];
    const float* bq = (const float*)d_in[2];
    const float* Wk = (const float*)d_in[3];
    const float* bk = (const float*)d_in[4];
    const float* Wv = (const float*)d_in[5];
    const float* bv = (const float*)d_in[6];
    const float* Wo = (const float*)d_in[7];
    const float* bo = (const float*)d_in[8];
    const float* gm = (const float*)d_in[9];
    const float* bt = (const float*)d_in[10];
    float* out = (float*)d_out;

    const size_t BASE_U16 = 262144u + 5u * 4194304u;
    const size_t need4 = (BASE_U16 + 2u * 4194304u) * 2 + 4u * 2u * 16384u * 4u;
    const size_t need3 = (BASE_U16 + 1u * 4194304u) * 2 + 3u * 2u * 16384u * 4u;
    int nz = (ws_size >= need4) ? 4 : (ws_size >= need3) ? 3 : 2;

    u16* W4 = (u16*)d_ws;
    u16* Qh = W4 + 262144;
    u16* Kh = Qh + 4194304;
    u16* Vt = Kh + 4194304;
    u16* V  = Vt + 4194304;
    u16* xh = V  + 4194304;
    u16* Op = V;
    float* lmp = (float*)(xh + 4194304 + (size_t)(nz > 2 ? nz - 2 : 0) * 4194304);
    u16* Woh = W4 + 196608;

    prep       <<<2048,            256,        0, stream>>>(x, Wq, Wk, Wv, Wo, xh, W4);
    proj_qkv   <<<dim3(256, 3),    256,        0, stream>>>(xh, W4, bq, bk, bv, Qh, Kh, V);
    transpose_v<<<dim3(64, 8, 8),  dim3(32,8), 0, stream>>>(V, Vt);
    attn       <<<dim3(32, 8, nz), 256,        0, stream>>>(Qh, Kh, Vt, Op, lmp);
    outproj_ln <<<256,             256,        0, stream>>>(Op, lmp, Woh, bo, gm, bt, out, nz);
}

// Round 12
// 203.330 us; speedup vs baseline: 1.4612x; 1.0018x over previous
//
#include <hip/hip_runtime.h>

typedef unsigned short u16;
typedef __attribute__((ext_vector_type(8))) _Float16 f16x8;
typedef __attribute__((ext_vector_type(4))) float f32x4;

#define MFMA_F16 __builtin_amdgcn_mfma_f32_16x16x32_f16

static __device__ __forceinline__ u16 f2h(float f) {
    return __builtin_bit_cast(u16, (_Float16)f);
}
static __device__ __forceinline__ ushort4 f4_to_h4(const float4 v) {
    ushort4 r;
    r.x = f2h(v.x); r.y = f2h(v.y); r.z = f2h(v.z); r.w = f2h(v.w);
    return r;
}

// ---------------------------------------------------------------------------
// Kernel 0: prep_w — convert Wq/Wk/Wv/Wo (4 x 16384 float4) fp32 -> fp16.
// ---------------------------------------------------------------------------
__global__ __launch_bounds__(256) void prep_w(
    const float* __restrict__ wq, const float* __restrict__ wk,
    const float* __restrict__ wv, const float* __restrict__ wo,
    u16* __restrict__ w4)
{
    const int tid = blockIdx.x * 256 + threadIdx.x;   // 16384 threads
    for (int i = tid; i < 65536; i += 16384) {
        const float* src = (i < 16384) ? wq : (i < 32768) ? wk
                         : (i < 49152) ? wv : wo;
        ((ushort4*)w4)[i] = f4_to_h4(((const float4*)src)[i & 16383]);
    }
}

// ---------------------------------------------------------------------------
// Kernel 1: Q/K/V projection, fp16 MFMA, x read fp32 (converted in staging).
// z==2 (V) writes its output TRANSPOSED directly to Vt[b][d][n] (ushort4
// pack over r) — replaces the separate transpose kernel.
// ---------------------------------------------------------------------------
__global__ __launch_bounds__(256) void proj_qkv(
    const float* __restrict__ X, const u16* __restrict__ w4,
    const float* __restrict__ bq, const float* __restrict__ bk,
    const float* __restrict__ bv,
    u16* __restrict__ Qh, u16* __restrict__ Kh, u16* __restrict__ Vt)
{
    const int z = blockIdx.y;
    const u16* __restrict__ W     = w4 + z * 65536;
    const float* __restrict__ bias = (z == 0) ? bq : (z == 1) ? bk : bv;

    const int m0   = blockIdx.x * 64;          // global row (b*2048 + n0)
    const int t    = threadIdx.x;
    const int w    = t >> 6;
    const int lane = t & 63;
    const int quad = lane >> 4;
    const int l16  = lane & 15;

    __shared__ __align__(16) u16 Xs[64 * 40];
    __shared__ __align__(16) u16 Ws[256 * 40];

    f32x4 acc[16];
#pragma unroll
    for (int i = 0; i < 16; ++i) acc[i] = f32x4{0.f, 0.f, 0.f, 0.f};

    for (int kc = 0; kc < 8; ++kc) {
        // X tile fp32 -> fp16: 64 rows x 8 float4-chunks = 512, 2/thread
#pragma unroll
        for (int i = 0; i < 2; ++i) {
            const int ch = i * 256 + t;
            const int row = ch >> 3, cg = ch & 7;
            const float4 v = *(const float4*)&X[(size_t)(m0 + row) * 256 + kc * 32 + cg * 4];
            *(ushort4*)&Xs[row * 40 + cg * 4] = f4_to_h4(v);
        }
        // W tile (fp16 pre-converted): 1024 int4-chunks, 4/thread
#pragma unroll
        for (int i = 0; i < 4; ++i) {
            const int ch = i * 256 + t;
            const int row = ch >> 2, cg = ch & 3;
            *(int4*)&Ws[row * 40 + cg * 8] =
                *(const int4*)&W[(size_t)row * 256 + kc * 32 + cg * 8];
        }
        __syncthreads();

        const f16x8 af = *(const f16x8*)&Xs[(w * 16 + l16) * 40 + quad * 8];
#pragma unroll
        for (int nt = 0; nt < 16; ++nt) {
            const f16x8 bf = *(const f16x8*)&Ws[(nt * 16 + l16) * 40 + quad * 8];
            acc[nt] = MFMA_F16(af, bf, acc[nt], 0, 0, 0);
        }
        __syncthreads();
    }

    if (z < 2) {
        u16* __restrict__ Y = (z == 0) ? Qh : Kh;
#pragma unroll
        for (int nt = 0; nt < 16; ++nt) {
            const int col = nt * 16 + l16;
            const float bb = bias[col];
#pragma unroll
            for (int r = 0; r < 4; ++r) {
                const int row = m0 + w * 16 + quad * 4 + r;
                Y[(size_t)row * 256 + col] = f2h(acc[nt][r] + bb);
            }
        }
    } else {
        // V: write transposed. d = col, n = n0 + w*16 + quad*4 + r.
        const int b  = m0 >> 11;
        const int n0 = m0 & 2047;
#pragma unroll
        for (int nt = 0; nt < 16; ++nt) {
            const int col = nt * 16 + l16;
            const float bb = bias[col];
            ushort4 h4;
            h4.x = f2h(acc[nt][0] + bb);
            h4.y = f2h(acc[nt][1] + bb);
            h4.z = f2h(acc[nt][2] + bb);
            h4.w = f2h(acc[nt][3] + bb);
            *(ushort4*)&Vt[(size_t)b * 524288 + (size_t)col * 2048
                           + n0 + w * 16 + quad * 4] = h4;
        }
    }
}

// ---------------------------------------------------------------------------
// Kernel 2: flash attention, transposed scores (R11 passing, unchanged).
// S^T = K Q^T, O^T = V^T P^T; split-K x nz (launched with nz=2).
// ---------------------------------------------------------------------------
__global__ __launch_bounds__(256) void attn(
    const u16* __restrict__ Qh, const u16* __restrict__ Kg,
    const u16* __restrict__ Vt, u16* __restrict__ Op, float* __restrict__ lmp)
{
    const int nz = gridDim.z;
    const int z  = blockIdx.z;
    const int tbase = 64 / nz, trem = 64 % nz;
    const int my_tiles = tbase + (z < trem ? 1 : 0);
    const int tile0    = tbase * z + (z < trem ? z : trem);

    const int b  = blockIdx.y;
    const int q0 = blockIdx.x * 64;
    const int t    = threadIdx.x;
    const int w    = t >> 6;
    const int lane = t & 63;
    const int quad = lane >> 4;
    const int l16  = lane & 15;

    __shared__ __align__(16) u16 smem[18688];   // 37376 B
    u16* Ks = smem;                // 32 x 264
    u16* Vs = smem + 8448;         // 256 x 40
    u16* Os = smem;                // epilogue reuse: 64 x 264

    f16x8 qf[8];
    {
        const size_t qrow = (size_t)(b * 2048 + q0 + w * 16 + l16) * 256;
#pragma unroll
        for (int kc = 0; kc < 8; ++kc)
            qf[kc] = *(const f16x8*)&Qh[qrow + kc * 32 + quad * 8];
    }

    f32x4 O[16];
#pragma unroll
    for (int i = 0; i < 16; ++i) O[i] = f32x4{0.f, 0.f, 0.f, 0.f};
    float mrow = -1e30f, lrow = 0.f;

    for (int it = 0; it < my_tiles; ++it) {
        const int kt = (tile0 + it) * 32;
#pragma unroll
        for (int i = 0; i < 4; ++i) {
            const int ch = i * 256 + t;
            const int row = ch >> 5, cg = ch & 31;
            const int prow = ((row >> 2) & 3) * 8 + (row >> 4) * 4 + (row & 3);
            *(int4*)&Ks[row * 264 + cg * 8] =
                *(const int4*)&Kg[(size_t)(b * 2048 + kt + prow) * 256 + cg * 8];
        }
#pragma unroll
        for (int i = 0; i < 4; ++i) {
            const int ch = i * 256 + t;
            const int row = ch >> 2, cg = ch & 3;
            *(int4*)&Vs[row * 40 + cg * 8] =
                *(const int4*)&Vt[(size_t)b * 524288 + (size_t)row * 2048 + kt + cg * 8];
        }
        __syncthreads();

        f32x4 S[2];
        S[0] = f32x4{0.f, 0.f, 0.f, 0.f};
        S[1] = f32x4{0.f, 0.f, 0.f, 0.f};
#pragma unroll
        for (int kc = 0; kc < 8; ++kc) {
#pragma unroll
            for (int kn = 0; kn < 2; ++kn) {
                const f16x8 kf = *(const f16x8*)&Ks[(kn * 16 + l16) * 264 + kc * 32 + quad * 8];
                S[kn] = MFMA_F16(kf, qf[kc], S[kn], 0, 0, 0);
            }
        }

        float mt = fmaxf(fmaxf(fmaxf(S[0][0], S[0][1]), fmaxf(S[0][2], S[0][3])),
                         fmaxf(fmaxf(S[1][0], S[1][1]), fmaxf(S[1][2], S[1][3])));
        mt = fmaxf(mt, __shfl_xor(mt, 16));
        mt = fmaxf(mt, __shfl_xor(mt, 32));
        const float mnew = fmaxf(mrow, mt);
        const float a = __expf(mrow - mnew);
        float p[2][4];
        float s = 0.f;
#pragma unroll
        for (int kn = 0; kn < 2; ++kn)
#pragma unroll
            for (int r = 0; r < 4; ++r) {
                p[kn][r] = __expf(S[kn][r] - mnew);
                s += p[kn][r];
            }
        s += __shfl_xor(s, 16);
        s += __shfl_xor(s, 32);
        lrow = a * lrow + s;
        mrow = mnew;

        if (__any(a < 1.f)) {
#pragma unroll
            for (int dv = 0; dv < 16; ++dv)
#pragma unroll
                for (int r = 0; r < 4; ++r) O[dv][r] *= a;
        }

        f16x8 pf;
#pragma unroll
        for (int kn = 0; kn < 2; ++kn)
#pragma unroll
            for (int r = 0; r < 4; ++r)
                pf[kn * 4 + r] = (_Float16)p[kn][r];

#pragma unroll
        for (int dvt = 0; dvt < 16; ++dvt) {
            const f16x8 vf = *(const f16x8*)&Vs[(dvt * 16 + l16) * 40 + quad * 8];
            O[dvt] = MFMA_F16(vf, pf, O[dvt], 0, 0, 0);
        }
        __syncthreads();
    }

    {
        const float rl = 1.0f / lrow;
#pragma unroll
        for (int dvt = 0; dvt < 16; ++dvt) {
            ushort4 h4;
            h4.x = f2h(O[dvt][0] * rl);
            h4.y = f2h(O[dvt][1] * rl);
            h4.z = f2h(O[dvt][2] * rl);
            h4.w = f2h(O[dvt][3] * rl);
            *(ushort4*)&Os[(w * 16 + l16) * 264 + dvt * 16 + quad * 4] = h4;
        }
        if (quad == 0) {
            const int grow = b * 2048 + q0 + w * 16 + l16;
            lmp[z * 16384 + grow]        = lrow;
            lmp[(nz + z) * 16384 + grow] = mrow;
        }
    }
    __syncthreads();

    u16* __restrict__ Oz = Op + (size_t)z * 4194304;
    {
        const int row = t >> 2;
#pragma unroll
        for (int i = 0; i < 8; ++i) {
            const int chunk = (t & 3) * 8 + i;
            *(int4*)&Oz[(size_t)(b * 2048 + q0 + row) * 256 + chunk * 8] =
                *(const int4*)&Os[row * 264 + chunk * 8];
        }
    }
}

// ---------------------------------------------------------------------------
// Kernel 3: combine 2 partials + out projection + LayerNorm + LeakyReLU.
// (R6-style two-term combine, nz=2 fixed.)
// ---------------------------------------------------------------------------
__global__ __launch_bounds__(256) void outproj_ln(
    const u16* __restrict__ Op, const float* __restrict__ lmp,
    const u16* __restrict__ Woh, const float* __restrict__ bo,
    const float* __restrict__ gamma, const float* __restrict__ beta,
    float* __restrict__ out)
{
    const int m0   = blockIdx.x * 64;
    const int t    = threadIdx.x;
    const int w    = t >> 6;
    const int lane = t & 63;
    const int quad = lane >> 4;
    const int l16  = lane & 15;

    __shared__ __align__(16) u16 Ls[64 * 40];
    __shared__ __align__(16) u16 Ws[256 * 40];
    __shared__ _Float16 w0s[64], w1s[64];

    if (t < 64) {
        const float l0 = lmp[m0 + t],          l1 = lmp[16384 + m0 + t];
        const float mm0 = lmp[32768 + m0 + t], mm1 = lmp[49152 + m0 + t];
        const float mm = fmaxf(mm0, mm1);
        const float u0 = l0 * __expf(mm0 - mm);
        const float u1 = l1 * __expf(mm1 - mm);
        const float inv = 1.0f / (u0 + u1);
        w0s[t] = (_Float16)(u0 * inv);
        w1s[t] = (_Float16)(u1 * inv);
    }
    __syncthreads();

    f32x4 acc[16];
#pragma unroll
    for (int i = 0; i < 16; ++i) acc[i] = f32x4{0.f, 0.f, 0.f, 0.f};

    for (int kc = 0; kc < 8; ++kc) {
        {
            const int row = t >> 2, cg = t & 3;
            const size_t off = (size_t)(m0 + row) * 256 + kc * 32 + cg * 8;
            const f16x8 o0 = __builtin_bit_cast(f16x8, *(const int4*)&Op[off]);
            const f16x8 o1 = __builtin_bit_cast(f16x8, *(const int4*)&Op[4194304 + off]);
            const _Float16 w0 = w0s[row], w1 = w1s[row];
            f16x8 lw;
#pragma unroll
            for (int j = 0; j < 8; ++j) lw[j] = o0[j] * w0 + o1[j] * w1;
            *(int4*)&Ls[row * 40 + cg * 8] = __builtin_bit_cast(int4, lw);
        }
#pragma unroll
        for (int i = 0; i < 4; ++i) {
            const int ch = i * 256 + t;
            const int row = ch >> 2, cg = ch & 3;
            *(int4*)&Ws[row * 40 + cg * 8] =
                *(const int4*)&Woh[(size_t)row * 256 + kc * 32 + cg * 8];
        }
        __syncthreads();

        const f16x8 af = *(const f16x8*)&Ls[(w * 16 + l16) * 40 + quad * 8];
#pragma unroll
        for (int nt = 0; nt < 16; ++nt) {
            const f16x8 bf = *(const f16x8*)&Ws[(nt * 16 + l16) * 40 + quad * 8];
            acc[nt] = MFMA_F16(af, bf, acc[nt], 0, 0, 0);
        }
        __syncthreads();
    }

    float g[16], bt[16], bb[16];
#pragma unroll
    for (int nt = 0; nt < 16; ++nt) {
        const int col = nt * 16 + l16;
        bb[nt] = bo[col]; g[nt] = gamma[col]; bt[nt] = beta[col];
    }

#pragma unroll
    for (int r = 0; r < 4; ++r) {
        float h[16];
        float sh = 0.f, sh2 = 0.f;
#pragma unroll
        for (int nt = 0; nt < 16; ++nt) {
            h[nt] = acc[nt][r] + bb[nt];
            sh  += h[nt];
            sh2 += h[nt] * h[nt];
        }
        sh  += __shfl_xor(sh, 1);  sh  += __shfl_xor(sh, 2);
        sh  += __shfl_xor(sh, 4);  sh  += __shfl_xor(sh, 8);
        sh2 += __shfl_xor(sh2, 1); sh2 += __shfl_xor(sh2, 2);
        sh2 += __shfl_xor(sh2, 4); sh2 += __shfl_xor(sh2, 8);
        const float mu  = sh * (1.f / 256.f);
        const float var = fmaxf(sh2 * (1.f / 256.f) - mu * mu, 0.f);
        const float rs  = rsqrtf(var + 1e-5f);
        const size_t row = (size_t)(m0 + w * 16 + quad * 4 + r) * 256;
#pragma unroll
        for (int nt = 0; nt < 16; ++nt) {
            const float hn = (h[nt] - mu) * rs * g[nt] + bt[nt];
            out[row + nt * 16 + l16] = (hn >= 0.f) ? hn : 0.01f * hn;
        }
    }
}

// ---------------------------------------------------------------------------
extern "C" void kernel_launch(void* const* d_in, const int* in_sizes, int n_in,
                              void* d_out, int out_size, void* d_ws, size_t ws_size,
                              hipStream_t stream)
{
    const float* x  = (const float*)d_in[0];
    const float* Wq = (const float*)d_in[1];
    const float* bq = (const float*)d_in[2];
    const float* Wk = (const float*)d_in[3];
    const float* bk = (const float*)d_in[4];
    const float* Wv = (const float*)d_in[5];
    const float* bv = (const float*)d_in[6];
    const float* Wo = (const float*)d_in[7];
    const float* bo = (const float*)d_in[8];
    const float* gm = (const float*)d_in[9];
    const float* bt = (const float*)d_in[10];
    float* out = (float*)d_out;

    // ws layout (u16): [W4 262144][Qh 4.19M][Kh 4.19M][Vt 4.19M][Op 2x4.19M][lmp]
    // Total ~42.7 MB (ws proven >= 59.8 MB by rounds 10/11 running nz=4).
    u16* W4 = (u16*)d_ws;
    u16* Qh = W4 + 262144;
    u16* Kh = Qh + 4194304;
    u16* Vt = Kh + 4194304;
    u16* Op = Vt + 4194304;
    float* lmp = (float*)(Op + 2 * 4194304);  // l[2][16384], m[2][16384]
    u16* Woh = W4 + 196608;

    prep_w     <<<64,             256, 0, stream>>>(Wq, Wk, Wv, Wo, W4);
    proj_qkv   <<<dim3(256, 3),   256, 0, stream>>>(x, W4, bq, bk, bv, Qh, Kh, Vt);
    attn       <<<dim3(32, 8, 2), 256, 0, stream>>>(Qh, Kh, Vt, Op, lmp);
    outproj_ln <<<256,            256, 0, stream>>>(Op, lmp, Woh, bo, gm, bt, out);
}

// Round 13
// 201.782 us; speedup vs baseline: 1.4724x; 1.0077x over previous
//
#include <hip/hip_runtime.h>

typedef unsigned short u16;
typedef __attribute__((ext_vector_type(8))) _Float16 f16x8;
typedef __attribute__((ext_vector_type(4))) float f32x4;

#define MFMA_F16 __builtin_amdgcn_mfma_f32_16x16x32_f16

static __device__ __forceinline__ u16 f2h(float f) {
    return __builtin_bit_cast(u16, (_Float16)f);
}
static __device__ __forceinline__ ushort4 f4_to_h4(const float4 v) {
    ushort4 r;
    r.x = f2h(v.x); r.y = f2h(v.y); r.z = f2h(v.z); r.w = f2h(v.w);
    return r;
}

// ---------------------------------------------------------------------------
// Kernel 0: prep_w — convert Wq/Wk/Wv/Wo (4 x 16384 float4) fp32 -> fp16.
// ---------------------------------------------------------------------------
__global__ __launch_bounds__(256) void prep_w(
    const float* __restrict__ wq, const float* __restrict__ wk,
    const float* __restrict__ wv, const float* __restrict__ wo,
    u16* __restrict__ w4)
{
    const int tid = blockIdx.x * 256 + threadIdx.x;   // 16384 threads
    for (int i = tid; i < 65536; i += 16384) {
        const float* src = (i < 16384) ? wq : (i < 32768) ? wk
                         : (i < 49152) ? wv : wo;
        ((ushort4*)w4)[i] = f4_to_h4(((const float4*)src)[i & 16383]);
    }
}

// ---------------------------------------------------------------------------
// Kernel 1: Q/K/V projection, fp16 MFMA, x read fp32 (converted in staging).
// ALL epilogues route through an LDS transpose (k-loop LDS is dead) so every
// global store is a coalesced int4:
//   z<2 : Ds[n_local][d]  64 x 264  -> row-major Qh/Kh stores
//   z==2: Dt[d][n_local] 256 x  72  -> Vt[b][d][n] stores (fused transpose)
// (R12's direct Vt ushort4 scatter at 4KB stride was the proj regression.)
// ---------------------------------------------------------------------------
__global__ __launch_bounds__(256) void proj_qkv(
    const float* __restrict__ X, const u16* __restrict__ w4,
    const float* __restrict__ bq, const float* __restrict__ bk,
    const float* __restrict__ bv,
    u16* __restrict__ Qh, u16* __restrict__ Kh, u16* __restrict__ Vt)
{
    const int z = blockIdx.y;
    const u16* __restrict__ W     = w4 + z * 65536;
    const float* __restrict__ bias = (z == 0) ? bq : (z == 1) ? bk : bv;

    const int m0   = blockIdx.x * 64;          // global row (b*2048 + n0)
    const int t    = threadIdx.x;
    const int w    = t >> 6;
    const int lane = t & 63;
    const int quad = lane >> 4;
    const int l16  = lane & 15;

    __shared__ __align__(16) u16 smem[18432];  // 36864 B
    u16* Xs = smem;            // 64 x 40 during k-loop
    u16* Ws = smem + 2560;     // 256 x 40 during k-loop

    f32x4 acc[16];
#pragma unroll
    for (int i = 0; i < 16; ++i) acc[i] = f32x4{0.f, 0.f, 0.f, 0.f};

    for (int kc = 0; kc < 8; ++kc) {
        // X tile fp32 -> fp16: 64 rows x 8 float4-chunks = 512, 2/thread
#pragma unroll
        for (int i = 0; i < 2; ++i) {
            const int ch = i * 256 + t;
            const int row = ch >> 3, cg = ch & 7;
            const float4 v = *(const float4*)&X[(size_t)(m0 + row) * 256 + kc * 32 + cg * 4];
            *(ushort4*)&Xs[row * 40 + cg * 4] = f4_to_h4(v);
        }
        // W tile (fp16 pre-converted): 1024 int4-chunks, 4/thread
#pragma unroll
        for (int i = 0; i < 4; ++i) {
            const int ch = i * 256 + t;
            const int row = ch >> 2, cg = ch & 3;
            *(int4*)&Ws[row * 40 + cg * 8] =
                *(const int4*)&W[(size_t)row * 256 + kc * 32 + cg * 8];
        }
        __syncthreads();

        const f16x8 af = *(const f16x8*)&Xs[(w * 16 + l16) * 40 + quad * 8];
#pragma unroll
        for (int nt = 0; nt < 16; ++nt) {
            const f16x8 bf = *(const f16x8*)&Ws[(nt * 16 + l16) * 40 + quad * 8];
            acc[nt] = MFMA_F16(af, bf, acc[nt], 0, 0, 0);
        }
        __syncthreads();   // also makes smem safe to reuse in the epilogue
    }

    if (z < 2) {
        u16* __restrict__ Y = (z == 0) ? Qh : Kh;
        // C-layout -> Ds[n][d] (scalar u16 stores, block-local)
#pragma unroll
        for (int nt = 0; nt < 16; ++nt) {
            const int col = nt * 16 + l16;
            const float bb = bias[col];
#pragma unroll
            for (int r = 0; r < 4; ++r)
                smem[(w * 16 + quad * 4 + r) * 264 + col] = f2h(acc[nt][r] + bb);
        }
        __syncthreads();
        // coalesced row-major stores: 64 rows x 32 int4 = 2048 chunks, 8/thread
#pragma unroll
        for (int i = 0; i < 8; ++i) {
            const int ch = i * 256 + t;
            const int row = ch >> 5, cg = ch & 31;
            *(int4*)&Y[(size_t)(m0 + row) * 256 + cg * 8] =
                *(const int4*)&smem[row * 264 + cg * 8];
        }
    } else {
        // C-layout -> Dt[d][n] (ushort4 over r), then coalesced Vt rows
        const int b  = m0 >> 11;
        const int n0 = m0 & 2047;
#pragma unroll
        for (int nt = 0; nt < 16; ++nt) {
            const int col = nt * 16 + l16;
            const float bb = bias[col];
            ushort4 h4;
            h4.x = f2h(acc[nt][0] + bb);
            h4.y = f2h(acc[nt][1] + bb);
            h4.z = f2h(acc[nt][2] + bb);
            h4.w = f2h(acc[nt][3] + bb);
            *(ushort4*)&smem[col * 72 + w * 16 + quad * 4] = h4;
        }
        __syncthreads();
        // 256 d-rows x 8 int4 chunks (64 n each) = 2048 chunks, 8/thread
#pragma unroll
        for (int i = 0; i < 8; ++i) {
            const int ch = i * 256 + t;
            const int row = ch >> 3, cg = ch & 7;
            *(int4*)&Vt[(size_t)b * 524288 + (size_t)row * 2048 + n0 + cg * 8] =
                *(const int4*)&smem[row * 72 + cg * 8];
        }
    }
}

// ---------------------------------------------------------------------------
// Kernel 2: flash attention, transposed scores (R11/R12 passing, unchanged).
// S^T = K Q^T, O^T = V^T P^T; split-K x nz (launched with nz=2).
// ---------------------------------------------------------------------------
__global__ __launch_bounds__(256) void attn(
    const u16* __restrict__ Qh, const u16* __restrict__ Kg,
    const u16* __restrict__ Vt, u16* __restrict__ Op, float* __restrict__ lmp)
{
    const int nz = gridDim.z;
    const int z  = blockIdx.z;
    const int tbase = 64 / nz, trem = 64 % nz;
    const int my_tiles = tbase + (z < trem ? 1 : 0);
    const int tile0    = tbase * z + (z < trem ? z : trem);

    const int b  = blockIdx.y;
    const int q0 = blockIdx.x * 64;
    const int t    = threadIdx.x;
    const int w    = t >> 6;
    const int lane = t & 63;
    const int quad = lane >> 4;
    const int l16  = lane & 15;

    __shared__ __align__(16) u16 smem[18688];   // 37376 B
    u16* Ks = smem;                // 32 x 264
    u16* Vs = smem + 8448;         // 256 x 40
    u16* Os = smem;                // epilogue reuse: 64 x 264

    f16x8 qf[8];
    {
        const size_t qrow = (size_t)(b * 2048 + q0 + w * 16 + l16) * 256;
#pragma unroll
        for (int kc = 0; kc < 8; ++kc)
            qf[kc] = *(const f16x8*)&Qh[qrow + kc * 32 + quad * 8];
    }

    f32x4 O[16];
#pragma unroll
    for (int i = 0; i < 16; ++i) O[i] = f32x4{0.f, 0.f, 0.f, 0.f};
    float mrow = -1e30f, lrow = 0.f;

    for (int it = 0; it < my_tiles; ++it) {
        const int kt = (tile0 + it) * 32;
#pragma unroll
        for (int i = 0; i < 4; ++i) {
            const int ch = i * 256 + t;
            const int row = ch >> 5, cg = ch & 31;
            const int prow = ((row >> 2) & 3) * 8 + (row >> 4) * 4 + (row & 3);
            *(int4*)&Ks[row * 264 + cg * 8] =
                *(const int4*)&Kg[(size_t)(b * 2048 + kt + prow) * 256 + cg * 8];
        }
#pragma unroll
        for (int i = 0; i < 4; ++i) {
            const int ch = i * 256 + t;
            const int row = ch >> 2, cg = ch & 3;
            *(int4*)&Vs[row * 40 + cg * 8] =
                *(const int4*)&Vt[(size_t)b * 524288 + (size_t)row * 2048 + kt + cg * 8];
        }
        __syncthreads();

        f32x4 S[2];
        S[0] = f32x4{0.f, 0.f, 0.f, 0.f};
        S[1] = f32x4{0.f, 0.f, 0.f, 0.f};
#pragma unroll
        for (int kc = 0; kc < 8; ++kc) {
#pragma unroll
            for (int kn = 0; kn < 2; ++kn) {
                const f16x8 kf = *(const f16x8*)&Ks[(kn * 16 + l16) * 264 + kc * 32 + quad * 8];
                S[kn] = MFMA_F16(kf, qf[kc], S[kn], 0, 0, 0);
            }
        }

        float mt = fmaxf(fmaxf(fmaxf(S[0][0], S[0][1]), fmaxf(S[0][2], S[0][3])),
                         fmaxf(fmaxf(S[1][0], S[1][1]), fmaxf(S[1][2], S[1][3])));
        mt = fmaxf(mt, __shfl_xor(mt, 16));
        mt = fmaxf(mt, __shfl_xor(mt, 32));
        const float mnew = fmaxf(mrow, mt);
        const float a = __expf(mrow - mnew);
        float p[2][4];
        float s = 0.f;
#pragma unroll
        for (int kn = 0; kn < 2; ++kn)
#pragma unroll
            for (int r = 0; r < 4; ++r) {
                p[kn][r] = __expf(S[kn][r] - mnew);
                s += p[kn][r];
            }
        s += __shfl_xor(s, 16);
        s += __shfl_xor(s, 32);
        lrow = a * lrow + s;
        mrow = mnew;

        if (__any(a < 1.f)) {
#pragma unroll
            for (int dv = 0; dv < 16; ++dv)
#pragma unroll
                for (int r = 0; r < 4; ++r) O[dv][r] *= a;
        }

        f16x8 pf;
#pragma unroll
        for (int kn = 0; kn < 2; ++kn)
#pragma unroll
            for (int r = 0; r < 4; ++r)
                pf[kn * 4 + r] = (_Float16)p[kn][r];

#pragma unroll
        for (int dvt = 0; dvt < 16; ++dvt) {
            const f16x8 vf = *(const f16x8*)&Vs[(dvt * 16 + l16) * 40 + quad * 8];
            O[dvt] = MFMA_F16(vf, pf, O[dvt], 0, 0, 0);
        }
        __syncthreads();
    }

    {
        const float rl = 1.0f / lrow;
#pragma unroll
        for (int dvt = 0; dvt < 16; ++dvt) {
            ushort4 h4;
            h4.x = f2h(O[dvt][0] * rl);
            h4.y = f2h(O[dvt][1] * rl);
            h4.z = f2h(O[dvt][2] * rl);
            h4.w = f2h(O[dvt][3] * rl);
            *(ushort4*)&Os[(w * 16 + l16) * 264 + dvt * 16 + quad * 4] = h4;
        }
        if (quad == 0) {
            const int grow = b * 2048 + q0 + w * 16 + l16;
            lmp[z * 16384 + grow]        = lrow;
            lmp[(nz + z) * 16384 + grow] = mrow;
        }
    }
    __syncthreads();

    u16* __restrict__ Oz = Op + (size_t)z * 4194304;
    {
        const int row = t >> 2;
#pragma unroll
        for (int i = 0; i < 8; ++i) {
            const int chunk = (t & 3) * 8 + i;
            *(int4*)&Oz[(size_t)(b * 2048 + q0 + row) * 256 + chunk * 8] =
                *(const int4*)&Os[row * 264 + chunk * 8];
        }
    }
}

// ---------------------------------------------------------------------------
// Kernel 3: combine 2 partials + out projection + LayerNorm + LeakyReLU.
// (R12 passing, unchanged)
// ---------------------------------------------------------------------------
__global__ __launch_bounds__(256) void outproj_ln(
    const u16* __restrict__ Op, const float* __restrict__ lmp,
    const u16* __restrict__ Woh, const float* __restrict__ bo,
    const float* __restrict__ gamma, const float* __restrict__ beta,
    float* __restrict__ out)
{
    const int m0   = blockIdx.x * 64;
    const int t    = threadIdx.x;
    const int w    = t >> 6;
    const int lane = t & 63;
    const int quad = lane >> 4;
    const int l16  = lane & 15;

    __shared__ __align__(16) u16 Ls[64 * 40];
    __shared__ __align__(16) u16 Ws[256 * 40];
    __shared__ _Float16 w0s[64], w1s[64];

    if (t < 64) {
        const float l0 = lmp[m0 + t],          l1 = lmp[16384 + m0 + t];
        const float mm0 = lmp[32768 + m0 + t], mm1 = lmp[49152 + m0 + t];
        const float mm = fmaxf(mm0, mm1);
        const float u0 = l0 * __expf(mm0 - mm);
        const float u1 = l1 * __expf(mm1 - mm);
        const float inv = 1.0f / (u0 + u1);
        w0s[t] = (_Float16)(u0 * inv);
        w1s[t] = (_Float16)(u1 * inv);
    }
    __syncthreads();

    f32x4 acc[16];
#pragma unroll
    for (int i = 0; i < 16; ++i) acc[i] = f32x4{0.f, 0.f, 0.f, 0.f};

    for (int kc = 0; kc < 8; ++kc) {
        {
            const int row = t >> 2, cg = t & 3;
            const size_t off = (size_t)(m0 + row) * 256 + kc * 32 + cg * 8;
            const f16x8 o0 = __builtin_bit_cast(f16x8, *(const int4*)&Op[off]);
            const f16x8 o1 = __builtin_bit_cast(f16x8, *(const int4*)&Op[4194304 + off]);
            const _Float16 w0 = w0s[row], w1 = w1s[row];
            f16x8 lw;
#pragma unroll
            for (int j = 0; j < 8; ++j) lw[j] = o0[j] * w0 + o1[j] * w1;
            *(int4*)&Ls[row * 40 + cg * 8] = __builtin_bit_cast(int4, lw);
        }
#pragma unroll
        for (int i = 0; i < 4; ++i) {
            const int ch = i * 256 + t;
            const int row = ch >> 2, cg = ch & 3;
            *(int4*)&Ws[row * 40 + cg * 8] =
                *(const int4*)&Woh[(size_t)row * 256 + kc * 32 + cg * 8];
        }
        __syncthreads();

        const f16x8 af = *(const f16x8*)&Ls[(w * 16 + l16) * 40 + quad * 8];
#pragma unroll
        for (int nt = 0; nt < 16; ++nt) {
            const f16x8 bf = *(const f16x8*)&Ws[(nt * 16 + l16) * 40 + quad * 8];
            acc[nt] = MFMA_F16(af, bf, acc[nt], 0, 0, 0);
        }
        __syncthreads();
    }

    float g[16], bt[16], bb[16];
#pragma unroll
    for (int nt = 0; nt < 16; ++nt) {
        const int col = nt * 16 + l16;
        bb[nt] = bo[col]; g[nt] = gamma[col]; bt[nt] = beta[col];
    }

#pragma unroll
    for (int r = 0; r < 4; ++r) {
        float h[16];
        float sh = 0.f, sh2 = 0.f;
#pragma unroll
        for (int nt = 0; nt < 16; ++nt) {
            h[nt] = acc[nt][r] + bb[nt];
            sh  += h[nt];
            sh2 += h[nt] * h[nt];
        }
        sh  += __shfl_xor(sh, 1);  sh  += __shfl_xor(sh, 2);
        sh  += __shfl_xor(sh, 4);  sh  += __shfl_xor(sh, 8);
        sh2 += __shfl_xor(sh2, 1); sh2 += __shfl_xor(sh2, 2);
        sh2 += __shfl_xor(sh2, 4); sh2 += __shfl_xor(sh2, 8);
        const float mu  = sh * (1.f / 256.f);
        const float var = fmaxf(sh2 * (1.f / 256.f) - mu * mu, 0.f);
        const float rs  = rsqrtf(var + 1e-5f);
        const size_t row = (size_t)(m0 + w * 16 + quad * 4 + r) * 256;
#pragma unroll
        for (int nt = 0; nt < 16; ++nt) {
            const float hn = (h[nt] - mu) * rs * g[nt] + bt[nt];
            out[row + nt * 16 + l16] = (hn >= 0.f) ? hn : 0.01f * hn;
        }
    }
}

// ---------------------------------------------------------------------------
extern "C" void kernel_launch(void* const* d_in, const int* in_sizes, int n_in,
                              void* d_out, int out_size, void* d_ws, size_t ws_size,
                              hipStream_t stream)
{
    const float* x  = (const float*)d_in[0];
    const float* Wq = (const float*)d_in[1];
    const float* bq = (const float*)d_in[2];
    const float* Wk = (const float*)d_in[3];
    const float* bk = (const float*)d_in[4];
    const float* Wv = (const float*)d_in[5];
    const float* bv = (const float*)d_in[6];
    const float* Wo = (const float*)d_in[7];
    const float* bo = (const float*)d_in[8];
    const float* gm = (const float*)d_in[9];
    const float* bt = (const float*)d_in[10];
    float* out = (float*)d_out;

    // ws layout (u16): [W4 262144][Qh 4.19M][Kh 4.19M][Vt 4.19M][Op 2x4.19M][lmp]
    u16* W4 = (u16*)d_ws;
    u16* Qh = W4 + 262144;
    u16* Kh = Qh + 4194304;
    u16* Vt = Kh + 4194304;
    u16* Op = Vt + 4194304;
    float* lmp = (float*)(Op + 2 * 4194304);  // l[2][16384], m[2][16384]
    u16* Woh = W4 + 196608;

    prep_w     <<<64,             256, 0, stream>>>(Wq, Wk, Wv, Wo, W4);
    proj_qkv   <<<dim3(256, 3),   256, 0, stream>>>(x, W4, bq, bk, bv, Qh, Kh, Vt);
    attn       <<<dim3(32, 8, 2), 256, 0, stream>>>(Qh, Kh, Vt, Op, lmp);
    outproj_ln <<<256,            256, 0, stream>>>(Op, lmp, Woh, bo, gm, bt, out);
}